// Round 1
// baseline (669.656 us; speedup 1.0000x reference)
//
#include <hip/hip_runtime.h>
#include <cfloat>
#include <cstddef>

// Problem constants (shapes fixed by the reference; N/E/B derived at runtime)
constexpr int KIN   = 128;   // IN_DIM
constexpr int KH    = 4;     // heads
constexpr int KC1   = 32;
constexpr int KC2   = 128;
constexpr int KQD   = 32;
constexpr int KT    = 50;
constexpr int KLH   = 128;
constexpr float BN_EPS = 1e-5f;

__device__ __forceinline__ float elu_f(float x)  { return x > 0.f ? x : expm1f(x); }
__device__ __forceinline__ float sigm_f(float x) { return 1.f / (1.f + expf(-x)); }
__device__ __forceinline__ float leaky_f(float x){ return x > 0.f ? x : 0.2f * x; }

// ---------------------------------------------------------------- K1: degree
__global__ void k_deg(const int* __restrict__ ei, int E, int* __restrict__ deg) {
    int e = blockIdx.x * blockDim.x + threadIdx.x;
    if (e < E) atomicAdd(&deg[ei[E + e]], 1);
}

// ------------------------------------------------- K2: exclusive scan (1 blk)
// offsets[0..n], cursor[i]=offsets[i], dinv[i]=rsqrt(deg[i]+1)
__global__ __launch_bounds__(1024)
void k_scan(const int* __restrict__ deg, int n, int* __restrict__ offsets,
            int* __restrict__ cursor, float* __restrict__ dinv) {
    __shared__ int wsum[16];
    __shared__ int carry_sh;
    int tid = threadIdx.x, lane = tid & 63, w = tid >> 6;
    if (tid == 0) { carry_sh = 0; offsets[0] = 0; }
    __syncthreads();
    for (int base = 0; base < n; base += 4096) {
        int i0 = base + tid * 4;
        int v[4];
        #pragma unroll
        for (int j = 0; j < 4; j++) v[j] = (i0 + j < n) ? deg[i0 + j] : 0;
        int tsum = v[0] + v[1] + v[2] + v[3];
        int sc = tsum;
        #pragma unroll
        for (int d = 1; d < 64; d <<= 1) {
            int o = __shfl_up(sc, d);
            if (lane >= d) sc += o;
        }
        __syncthreads();                 // protect wsum from prev-iter readers
        if (lane == 63) wsum[w] = sc;
        __syncthreads();
        if (w == 0) {
            int xx = (lane < 16) ? wsum[lane] : 0;
            #pragma unroll
            for (int d = 1; d < 16; d <<= 1) {
                int o = __shfl_up(xx, d);
                if (lane >= d) xx += o;
            }
            if (lane < 16) wsum[lane] = xx;
        }
        __syncthreads();
        int carry = carry_sh;
        int woff  = (w > 0) ? wsum[w - 1] : 0;
        int run   = carry + woff + sc - tsum;     // exclusive prefix at i0
        #pragma unroll
        for (int j = 0; j < 4; j++) {
            int i = i0 + j;
            if (i < n) {
                cursor[i]      = run;
                offsets[i + 1] = run + v[j];
                dinv[i]        = rsqrtf((float)(v[j] + 1));
                run += v[j];
            }
        }
        __syncthreads();
        if (tid == 0) carry_sh = carry + wsum[15];
    }
}

// ---------------------------------------------------------------- K3: fill
__global__ void k_fill(const int* __restrict__ ei, int E, int* __restrict__ cursor,
                       int* __restrict__ csr_src) {
    int e = blockIdx.x * blockDim.x + threadIdx.x;
    if (e < E) {
        int s = ei[e], d = ei[E + e];
        int pos = atomicAdd(&cursor[d], 1);
        csr_src[pos] = s;
    }
}

// ------------------------------------- K4/K6: 128x128 GEMM, W in LDS (k-split)
// Y[r, :] = X[r, :] @ W ; optional per-head attention dots (GAT)
template <bool ATT>
__global__ __launch_bounds__(512)
void k_gemm128(const float* __restrict__ X, const float* __restrict__ W,
               float* __restrict__ Y, int nrows,
               const float* __restrict__ attS, const float* __restrict__ attD,
               float* __restrict__ a_src, float* __restrict__ a_dst) {
    __shared__ float w_sh[64 * 128];      // 32 KB (half of W)
    __shared__ float x_sh[32 * 129];      // 16.5 KB, padded rows
    __shared__ float as_sh[128], ad_sh[128];
    int tid = threadIdx.x;
    if (ATT && tid < 128) { as_sh[tid] = attS[tid]; ad_sh[tid] = attD[tid]; }
    int row_l = tid >> 4;       // 0..31
    int cg    = tid & 15;       // 0..15
    int c0    = cg * 8;
    int nch = (nrows + 31) / 32;
    for (int ch = blockIdx.x; ch < nch; ch += gridDim.x) {
        int r0 = ch * 32;
        __syncthreads();
        for (int idx = tid; idx < 32 * 128; idx += 512) {
            int rr = idx >> 7, cc = idx & 127;
            int gr = r0 + rr;
            x_sh[rr * 129 + cc] = (gr < nrows) ? X[(size_t)gr * 128 + cc] : 0.f;
        }
        float acc[8];
        #pragma unroll
        for (int i = 0; i < 8; i++) acc[i] = 0.f;
        #pragma unroll
        for (int kh = 0; kh < 2; kh++) {
            __syncthreads();
            for (int idx = tid; idx < 64 * 128; idx += 512)
                w_sh[idx] = W[kh * 64 * 128 + idx];
            __syncthreads();
            const float* xr = &x_sh[row_l * 129 + kh * 64];
            #pragma unroll 4
            for (int k = 0; k < 64; k++) {
                float xv = xr[k];
                float4 w0 = *reinterpret_cast<const float4*>(&w_sh[k * 128 + c0]);
                float4 w1 = *reinterpret_cast<const float4*>(&w_sh[k * 128 + c0 + 4]);
                acc[0] += xv * w0.x; acc[1] += xv * w0.y;
                acc[2] += xv * w0.z; acc[3] += xv * w0.w;
                acc[4] += xv * w1.x; acc[5] += xv * w1.y;
                acc[6] += xv * w1.z; acc[7] += xv * w1.w;
            }
        }
        int r = r0 + row_l;
        if (r < nrows) {
            float4* yp = reinterpret_cast<float4*>(&Y[(size_t)r * 128 + c0]);
            yp[0] = make_float4(acc[0], acc[1], acc[2], acc[3]);
            yp[1] = make_float4(acc[4], acc[5], acc[6], acc[7]);
            if (ATT) {
                float ps = 0.f, pd = 0.f;
                #pragma unroll
                for (int i = 0; i < 8; i++) {
                    ps += acc[i] * as_sh[c0 + i];
                    pd += acc[i] * ad_sh[c0 + i];
                }
                ps += __shfl_xor(ps, 1); ps += __shfl_xor(ps, 2);
                pd += __shfl_xor(pd, 1); pd += __shfl_xor(pd, 2);
                if ((cg & 3) == 0) {
                    int h = cg >> 2;
                    a_src[r * 4 + h] = ps;
                    a_dst[r * 4 + h] = pd;
                }
            }
        }
    }
}

// -------------------------- K5: GAT aggregate per dst node (wave per node)
__global__ __launch_bounds__(256)
void k_gat_agg(const int* __restrict__ offsets, const int* __restrict__ csr_src,
               const float* __restrict__ a_src, const float* __restrict__ a_dst,
               const float* __restrict__ xw, const float* __restrict__ bias,
               const float* __restrict__ g1, const float* __restrict__ b1,
               const float* __restrict__ mu1, const float* __restrict__ var1,
               float* __restrict__ hout, int n) {
    int lane = threadIdx.x & 63;
    int wid  = (blockIdx.x * blockDim.x + threadIdx.x) >> 6;
    int nw   = (gridDim.x * blockDim.x) >> 6;
    for (int node = wid; node < n; node += nw) {
        int beg = offsets[node], end = offsets[node + 1];
        int rowlen = end - beg, total = rowlen + 1;   // + self loop
        float ad0 = a_dst[node * 4 + 0], ad1 = a_dst[node * 4 + 1];
        float ad2 = a_dst[node * 4 + 2], ad3 = a_dst[node * 4 + 3];
        // per-lane edge prefetch (deg ~ Poisson(16), virtually always < 64)
        int sv = (lane < rowlen) ? csr_src[beg + lane] : node;
        float el0 = leaky_f(a_src[sv * 4 + 0] + ad0);
        float el1 = leaky_f(a_src[sv * 4 + 1] + ad1);
        float el2 = leaky_f(a_src[sv * 4 + 2] + ad2);
        float el3 = leaky_f(a_src[sv * 4 + 3] + ad3);
        float m[4], s[4];
        #pragma unroll
        for (int h = 0; h < 4; h++) { m[h] = -FLT_MAX; s[h] = 0.f; }
        if (lane < total) {
            m[0] = el0; m[1] = el1; m[2] = el2; m[3] = el3;
            s[0] = s[1] = s[2] = s[3] = 1.f;
        }
        for (int i = lane + 64; i < total; i += 64) {   // rare tail
            int src = (i < rowlen) ? csr_src[beg + i] : node;
            float e[4];
            e[0] = leaky_f(a_src[src * 4 + 0] + ad0);
            e[1] = leaky_f(a_src[src * 4 + 1] + ad1);
            e[2] = leaky_f(a_src[src * 4 + 2] + ad2);
            e[3] = leaky_f(a_src[src * 4 + 3] + ad3);
            #pragma unroll
            for (int h = 0; h < 4; h++) {
                float M = fmaxf(m[h], e[h]);
                s[h] = s[h] * expf(m[h] - M) + expf(e[h] - M);
                m[h] = M;
            }
        }
        #pragma unroll
        for (int off = 32; off; off >>= 1) {
            #pragma unroll
            for (int h = 0; h < 4; h++) {
                float mo = __shfl_xor(m[h], off);
                float so = __shfl_xor(s[h], off);
                float M  = fmaxf(m[h], mo);
                s[h] = s[h] * expf(m[h] - M) + so * expf(mo - M);
                m[h] = M;
            }
        }
        float inv[4];
        #pragma unroll
        for (int h = 0; h < 4; h++) inv[h] = 1.f / (s[h] + 1e-16f);
        bool hiHalf = (lane & 32) != 0;
        float m_lo = hiHalf ? m[1] : m[0], inv_lo = hiHalf ? inv[1] : inv[0];
        float m_hi = hiHalf ? m[3] : m[2], inv_hi = hiHalf ? inv[3] : inv[2];
        float acc0 = 0.f, acc1 = 0.f;
        for (int i = 0; i < total; i++) {
            float e_lo, e_hi;
            int src;
            if (i < 64) {
                float a0 = __shfl(el0, i), a1 = __shfl(el1, i);
                float a2 = __shfl(el2, i), a3 = __shfl(el3, i);
                e_lo = hiHalf ? a1 : a0;
                e_hi = hiHalf ? a3 : a2;
                src  = __shfl(sv, i);
            } else {
                src = (i < rowlen) ? csr_src[beg + i] : node;
                int b4 = src * 4;
                e_lo = leaky_f(a_src[b4 + (hiHalf ? 1 : 0)] + (hiHalf ? ad1 : ad0));
                e_hi = leaky_f(a_src[b4 + (hiHalf ? 3 : 2)] + (hiHalf ? ad3 : ad2));
            }
            float al_lo = expf(e_lo - m_lo) * inv_lo;
            float al_hi = expf(e_hi - m_hi) * inv_hi;
            const float* xr = &xw[(size_t)src * 128];
            acc0 += al_lo * xr[lane];
            acc1 += al_hi * xr[64 + lane];
        }
        int cA = lane, cB = lane + 64;
        float vA = elu_f(acc0 + bias[cA]);
        float vB = elu_f(acc1 + bias[cB]);
        vA = g1[cA] * (vA - mu1[cA]) * rsqrtf(var1[cA] + BN_EPS) + b1[cA];
        vB = g1[cB] * (vB - mu1[cB]) * rsqrtf(var1[cB] + BN_EPS) + b1[cB];
        hout[(size_t)node * 128 + cA] = vA;
        hout[(size_t)node * 128 + cB] = vB;
    }
}

// -------------------------- K7: GCN aggregate per dst node + gate dot
__global__ __launch_bounds__(256)
void k_gcn_agg(const int* __restrict__ offsets, const int* __restrict__ csr_src,
               const float* __restrict__ dinv, const float* __restrict__ hw,
               const float* __restrict__ bias,
               const float* __restrict__ g2, const float* __restrict__ b2,
               const float* __restrict__ mu2, const float* __restrict__ var2,
               const float* __restrict__ gateW, const float* __restrict__ gateB,
               float* __restrict__ h2, float* __restrict__ gate, int n) {
    int lane = threadIdx.x & 63;
    int wid  = (blockIdx.x * blockDim.x + threadIdx.x) >> 6;
    int nw   = (gridDim.x * blockDim.x) >> 6;
    for (int node = wid; node < n; node += nw) {
        int beg = offsets[node], end = offsets[node + 1];
        int rowlen = end - beg;
        float dn = dinv[node];
        int   sv  = (lane < rowlen) ? csr_src[beg + lane] : node;
        float dvl = dinv[sv];
        const float* hr_self = &hw[(size_t)node * 128];
        float acc0 = dn * dn * hr_self[lane];
        float acc1 = dn * dn * hr_self[64 + lane];
        for (int i = 0; i < rowlen; i++) {
            int src; float w;
            if (i < 64) { src = __shfl(sv, i); w = __shfl(dvl, i) * dn; }
            else        { src = csr_src[beg + i]; w = dinv[src] * dn; }
            const float* hr = &hw[(size_t)src * 128];
            acc0 += w * hr[lane];
            acc1 += w * hr[64 + lane];
        }
        int cA = lane, cB = lane + 64;
        float vA = elu_f(acc0 + bias[cA]);
        float vB = elu_f(acc1 + bias[cB]);
        vA = g2[cA] * (vA - mu2[cA]) * rsqrtf(var2[cA] + BN_EPS) + b2[cA];
        vB = g2[cB] * (vB - mu2[cB]) * rsqrtf(var2[cB] + BN_EPS) + b2[cB];
        h2[(size_t)node * 128 + cA] = vA;
        h2[(size_t)node * 128 + cB] = vB;
        float p = vA * gateW[cA] + vB * gateW[cB];
        #pragma unroll
        for (int off = 32; off; off >>= 1) p += __shfl_xor(p, off);
        if (lane == 0) gate[node] = p + gateB[0];
    }
}

// -------------------------- K8: GlobalAttention pool, one block per graph
__device__ __forceinline__ int lbound(const int* a, int n, int key) {
    int lo = 0, hi = n;
    while (lo < hi) { int mid = (lo + hi) >> 1; if (a[mid] < key) lo = mid + 1; else hi = mid; }
    return lo;
}

__global__ __launch_bounds__(256)
void k_pool(const int* __restrict__ batch, const float* __restrict__ gate,
            const float* __restrict__ h2, float* __restrict__ grep, int n) {
    int b = blockIdx.x, tid = threadIdx.x;
    __shared__ float red[256];
    __shared__ float sc_sh[256];
    int start = lbound(batch, n, b);
    int end   = lbound(batch, n, b + 1);
    float m = -FLT_MAX;
    for (int i = start + tid; i < end; i += 256) m = fmaxf(m, gate[i]);
    red[tid] = m; __syncthreads();
    for (int s2 = 128; s2 > 0; s2 >>= 1) {
        if (tid < s2) red[tid] = fmaxf(red[tid], red[tid + s2]);
        __syncthreads();
    }
    m = red[0]; __syncthreads();
    float s = 0.f;
    for (int i = start + tid; i < end; i += 256) s += expf(gate[i] - m);
    red[tid] = s; __syncthreads();
    for (int s2 = 128; s2 > 0; s2 >>= 1) {
        if (tid < s2) red[tid] += red[tid + s2];
        __syncthreads();
    }
    float inv = 1.f / (red[0] + 1e-16f);
    __syncthreads();
    int j = tid & 127, half = tid >> 7;
    float acc = 0.f;
    for (int base = start; base < end; base += 256) {
        int cnt = min(256, end - base);
        __syncthreads();
        if (tid < cnt) sc_sh[tid] = expf(gate[base + tid] - m) * inv;
        __syncthreads();
        for (int ii = half; ii < cnt; ii += 2)
            acc += sc_sh[ii] * h2[(size_t)(base + ii) * 128 + j];
    }
    red[tid] = acc; __syncthreads();
    if (half == 0) grep[b * 128 + j] = red[j] + red[128 + j];
}

// -------------------------- K9: LSTM (block per batch elem) + fused final FC
__global__ __launch_bounds__(512, 2)
void k_lstm(const float* __restrict__ quant, const float* __restrict__ Wih,
            const float* __restrict__ Whh, const float* __restrict__ bih,
            const float* __restrict__ bhh, const float* __restrict__ grep,
            const float* __restrict__ fcW, const float* __restrict__ fcB,
            float* __restrict__ out) {
    int b = blockIdx.x, t = threadIdx.x;
    __shared__ float x_sh[KT * KQD];       // 1600
    __shared__ float h_sh[KLH];
    __shared__ float g_sh[4 * KLH];        // 512
    for (int idx = t; idx < KT * KQD; idx += 512)
        x_sh[idx] = quant[(size_t)b * (KT * KQD) + idx];
    float wih[KQD];
    #pragma unroll
    for (int k = 0; k < KQD; k++) wih[k] = Wih[t * KQD + k];
    float whh[KLH];
    #pragma unroll
    for (int k = 0; k < KLH; k++) whh[k] = Whh[t * KLH + k];
    float bias = bih[t] + bhh[t];
    float c = 0.f;
    if (t < KLH) h_sh[t] = 0.f;
    __syncthreads();
    for (int step = 0; step < KT; step++) {
        float a0 = 0.f, a1 = 0.f, a2 = 0.f, a3 = 0.f;
        #pragma unroll
        for (int k = 0; k < KLH; k += 4) {
            a0 += whh[k]     * h_sh[k];
            a1 += whh[k + 1] * h_sh[k + 1];
            a2 += whh[k + 2] * h_sh[k + 2];
            a3 += whh[k + 3] * h_sh[k + 3];
        }
        const float* xs = &x_sh[step * KQD];
        #pragma unroll
        for (int k = 0; k < KQD; k += 4) {
            a0 += wih[k]     * xs[k];
            a1 += wih[k + 1] * xs[k + 1];
            a2 += wih[k + 2] * xs[k + 2];
            a3 += wih[k + 3] * xs[k + 3];
        }
        g_sh[t] = (a0 + a1) + (a2 + a3) + bias;
        __syncthreads();
        if (t < KLH) {
            float ig = sigm_f(g_sh[t]);
            float fg = sigm_f(g_sh[KLH + t]);
            float gg = tanhf(g_sh[2 * KLH + t]);
            float og = sigm_f(g_sh[3 * KLH + t]);
            c = fg * c + ig * gg;
            h_sh[t] = og * tanhf(c);
        }
        __syncthreads();
    }
    if (t < KLH)
        g_sh[t] = fcW[t] * grep[b * 128 + t] + fcW[128 + t] * h_sh[t];
    __syncthreads();
    for (int s2 = 64; s2 > 0; s2 >>= 1) {
        if (t < s2) g_sh[t] += g_sh[t + s2];
        __syncthreads();
    }
    if (t == 0) out[b] = g_sh[0] + fcB[0];
}

// ----------------------------------------------------------------- launcher
extern "C" void kernel_launch(void* const* d_in, const int* in_sizes, int n_in,
                              void* d_out, int out_size, void* d_ws, size_t ws_size,
                              hipStream_t stream) {
    const float* x     = (const float*)d_in[0];
    const int*   ei    = (const int*)  d_in[1];
    const int*   batch = (const int*)  d_in[2];
    const float* quant = (const float*)d_in[3];
    const float* gatW  = (const float*)d_in[4];
    const float* attS  = (const float*)d_in[5];
    const float* attD  = (const float*)d_in[6];
    const float* gatB  = (const float*)d_in[7];
    const float* bn1g  = (const float*)d_in[8];
    const float* bn1b  = (const float*)d_in[9];
    const float* bn1m  = (const float*)d_in[10];
    const float* bn1v  = (const float*)d_in[11];
    const float* gcnW  = (const float*)d_in[12];
    const float* gcnB  = (const float*)d_in[13];
    const float* bn2g  = (const float*)d_in[14];
    const float* bn2b  = (const float*)d_in[15];
    const float* bn2m  = (const float*)d_in[16];
    const float* bn2v  = (const float*)d_in[17];
    const float* gateW = (const float*)d_in[18];
    const float* gateB = (const float*)d_in[19];
    const float* Wih   = (const float*)d_in[20];
    const float* Whh   = (const float*)d_in[21];
    const float* bih   = (const float*)d_in[22];
    const float* bhh   = (const float*)d_in[23];
    const float* fcW   = (const float*)d_in[24];
    const float* fcB   = (const float*)d_in[25];

    int N = in_sizes[0] / KIN;
    int E = in_sizes[1] / 2;
    int B = in_sizes[3] / (KT * KQD);

    char* ws = (char*)d_ws;
    size_t off = 0;
    auto alloc = [&](size_t bytes) -> void* {
        void* p = ws + off;
        off += (bytes + 511) & ~(size_t)511;
        return p;
    };
    int*   deg     = (int*)  alloc((size_t)N * 4);
    int*   offsets = (int*)  alloc((size_t)(N + 1) * 4);
    int*   cursor  = (int*)  alloc((size_t)N * 4);
    float* dinv    = (float*)alloc((size_t)N * 4);
    int*   csr_src = (int*)  alloc((size_t)E * 4);
    float* a_src   = (float*)alloc((size_t)N * 16);
    float* a_dst   = (float*)alloc((size_t)N * 16);
    float* xw      = (float*)alloc((size_t)N * 512);   // xw, then reused as hw
    float* hbuf    = (float*)alloc((size_t)N * 512);   // h_bn, then reused as h2
    float* gate    = (float*)alloc((size_t)N * 4);
    float* grep    = (float*)alloc((size_t)B * 512);

    hipMemsetAsync(deg, 0, (size_t)N * 4, stream);
    int eb = (E + 255) / 256;
    k_deg <<<eb, 256, 0, stream>>>(ei, E, deg);
    k_scan<<<1, 1024, 0, stream>>>(deg, N, offsets, cursor, dinv);
    k_fill<<<eb, 256, 0, stream>>>(ei, E, cursor, csr_src);

    k_gemm128<true ><<<768, 512, 0, stream>>>(x, gatW, xw, N, attS, attD, a_src, a_dst);
    k_gat_agg<<<2048, 256, 0, stream>>>(offsets, csr_src, a_src, a_dst, xw, gatB,
                                        bn1g, bn1b, bn1m, bn1v, hbuf, N);
    k_gemm128<false><<<768, 512, 0, stream>>>(hbuf, gcnW, xw, N,
                                              nullptr, nullptr, nullptr, nullptr);
    k_gcn_agg<<<2048, 256, 0, stream>>>(offsets, csr_src, dinv, xw, gcnB,
                                        bn2g, bn2b, bn2m, bn2v, gateW, gateB,
                                        hbuf, gate, N);
    k_pool<<<B, 256, 0, stream>>>(batch, gate, hbuf, grep, N);
    k_lstm<<<B, 512, 0, stream>>>(quant, Wih, Whh, bih, bhh, grep, fcW, fcB,
                                  (float*)d_out);
}

// Round 2
// 585.808 us; speedup vs baseline: 1.1431x; 1.1431x over previous
//
#include <hip/hip_runtime.h>
#include <cfloat>
#include <cstddef>

constexpr int KIN   = 128;
constexpr int KQD   = 32;
constexpr int KT    = 50;
constexpr int KLH   = 128;
constexpr float BN_EPS = 1e-5f;

__device__ __forceinline__ float elu_f(float x)  { return x > 0.f ? x : expm1f(x); }
__device__ __forceinline__ float sigm_f(float x) { return 1.f / (1.f + expf(-x)); }
__device__ __forceinline__ float leaky_f(float x){ return x > 0.f ? x : 0.2f * x; }

// ---------------------------------------------------------------- K1: degree
__global__ void k_deg(const int* __restrict__ ei, int E, int* __restrict__ deg) {
    int e = blockIdx.x * blockDim.x + threadIdx.x;
    if (e < E) atomicAdd(&deg[ei[E + e]], 1);
}

// ------------------------------------------------- K2: exclusive scan (1 blk)
__global__ __launch_bounds__(1024)
void k_scan(const int* __restrict__ deg, int n, int* __restrict__ offsets,
            int* __restrict__ cursor, float* __restrict__ dinv) {
    __shared__ int wsum[16];
    __shared__ int carry_sh;
    int tid = threadIdx.x, lane = tid & 63, w = tid >> 6;
    if (tid == 0) { carry_sh = 0; offsets[0] = 0; }
    __syncthreads();
    for (int base = 0; base < n; base += 4096) {
        int i0 = base + tid * 4;
        int v[4];
        #pragma unroll
        for (int j = 0; j < 4; j++) v[j] = (i0 + j < n) ? deg[i0 + j] : 0;
        int tsum = v[0] + v[1] + v[2] + v[3];
        int sc = tsum;
        #pragma unroll
        for (int d = 1; d < 64; d <<= 1) {
            int o = __shfl_up(sc, d);
            if (lane >= d) sc += o;
        }
        __syncthreads();
        if (lane == 63) wsum[w] = sc;
        __syncthreads();
        if (w == 0) {
            int xx = (lane < 16) ? wsum[lane] : 0;
            #pragma unroll
            for (int d = 1; d < 16; d <<= 1) {
                int o = __shfl_up(xx, d);
                if (lane >= d) xx += o;
            }
            if (lane < 16) wsum[lane] = xx;
        }
        __syncthreads();
        int carry = carry_sh;
        int woff  = (w > 0) ? wsum[w - 1] : 0;
        int run   = carry + woff + sc - tsum;
        #pragma unroll
        for (int j = 0; j < 4; j++) {
            int i = i0 + j;
            if (i < n) {
                cursor[i]      = run;
                offsets[i + 1] = run + v[j];
                dinv[i]        = rsqrtf((float)(v[j] + 1));
                run += v[j];
            }
        }
        __syncthreads();
        if (tid == 0) carry_sh = carry + wsum[15];
    }
}

// ---------------------------------------------------------------- K3: fill
__global__ void k_fill(const int* __restrict__ ei, int E, int* __restrict__ cursor,
                       int* __restrict__ csr_src) {
    int e = blockIdx.x * blockDim.x + threadIdx.x;
    if (e < E) {
        int s = ei[e], d = ei[E + e];
        int pos = atomicAdd(&cursor[d], 1);
        csr_src[pos] = s;
    }
}

// ------------------------------------- K4/K6: 128x128 GEMM, W in LDS (k-split)
template <bool ATT>
__global__ __launch_bounds__(512)
void k_gemm128(const float* __restrict__ X, const float* __restrict__ W,
               float* __restrict__ Y, int nrows,
               const float* __restrict__ attS, const float* __restrict__ attD,
               float* __restrict__ a_src, float* __restrict__ a_dst) {
    __shared__ float w_sh[64 * 128];
    __shared__ float x_sh[32 * 129];
    __shared__ float as_sh[128], ad_sh[128];
    int tid = threadIdx.x;
    if (ATT && tid < 128) { as_sh[tid] = attS[tid]; ad_sh[tid] = attD[tid]; }
    int row_l = tid >> 4;
    int cg    = tid & 15;
    int c0    = cg * 8;
    int nch = (nrows + 31) / 32;
    for (int ch = blockIdx.x; ch < nch; ch += gridDim.x) {
        int r0 = ch * 32;
        __syncthreads();
        for (int idx = tid; idx < 32 * 128; idx += 512) {
            int rr = idx >> 7, cc = idx & 127;
            int gr = r0 + rr;
            x_sh[rr * 129 + cc] = (gr < nrows) ? X[(size_t)gr * 128 + cc] : 0.f;
        }
        float acc[8];
        #pragma unroll
        for (int i = 0; i < 8; i++) acc[i] = 0.f;
        #pragma unroll
        for (int kh = 0; kh < 2; kh++) {
            __syncthreads();
            for (int idx = tid; idx < 64 * 128; idx += 512)
                w_sh[idx] = W[kh * 64 * 128 + idx];
            __syncthreads();
            const float* xr = &x_sh[row_l * 129 + kh * 64];
            #pragma unroll 4
            for (int k = 0; k < 64; k++) {
                float xv = xr[k];
                float4 w0 = *reinterpret_cast<const float4*>(&w_sh[k * 128 + c0]);
                float4 w1 = *reinterpret_cast<const float4*>(&w_sh[k * 128 + c0 + 4]);
                acc[0] += xv * w0.x; acc[1] += xv * w0.y;
                acc[2] += xv * w0.z; acc[3] += xv * w0.w;
                acc[4] += xv * w1.x; acc[5] += xv * w1.y;
                acc[6] += xv * w1.z; acc[7] += xv * w1.w;
            }
        }
        int r = r0 + row_l;
        if (r < nrows) {
            float4* yp = reinterpret_cast<float4*>(&Y[(size_t)r * 128 + c0]);
            yp[0] = make_float4(acc[0], acc[1], acc[2], acc[3]);
            yp[1] = make_float4(acc[4], acc[5], acc[6], acc[7]);
            if (ATT) {
                float ps = 0.f, pd = 0.f;
                #pragma unroll
                for (int i = 0; i < 8; i++) {
                    ps += acc[i] * as_sh[c0 + i];
                    pd += acc[i] * ad_sh[c0 + i];
                }
                ps += __shfl_xor(ps, 1); ps += __shfl_xor(ps, 2);
                pd += __shfl_xor(pd, 1); pd += __shfl_xor(pd, 2);
                if ((cg & 3) == 0) {
                    int h = cg >> 2;
                    a_src[r * 4 + h] = ps;
                    a_dst[r * 4 + h] = pd;
                }
            }
        }
    }
}

// -------------------------- K5: GAT aggregate — wave/node, alpha staged in LDS
__global__ __launch_bounds__(256)
void k_gat_agg(const int* __restrict__ offsets, const int* __restrict__ csr_src,
               const float* __restrict__ a_src, const float* __restrict__ a_dst,
               const float* __restrict__ xw, const float* __restrict__ bias,
               const float* __restrict__ g1, const float* __restrict__ b1,
               const float* __restrict__ mu1, const float* __restrict__ var1,
               float* __restrict__ hout, int n) {
    __shared__ int   src_sh[4][64];
    __shared__ float al_sh[4][4][64];     // [wave][head][edge]
    int lane = threadIdx.x & 63;
    int wv   = threadIdx.x >> 6;
    int wid  = (blockIdx.x * blockDim.x + threadIdx.x) >> 6;
    int nw   = (gridDim.x * blockDim.x) >> 6;
    int hA = lane >> 5;       // head for col = lane
    int hB = hA + 2;          // head for col = lane + 64
    for (int node = wid; node < n; node += nw) {
        int beg = offsets[node], end = offsets[node + 1];
        int rowlen = end - beg, total = rowlen + 1;   // + self loop
        float4 adv = *reinterpret_cast<const float4*>(&a_dst[(size_t)node * 4]);
        // chunk-0 prefetch (deg ~ Poisson(16); total <= 64 virtually always)
        int sv = (lane < rowlen) ? csr_src[beg + lane] : node;
        float4 as4 = *reinterpret_cast<const float4*>(&a_src[(size_t)sv * 4]);
        float e0 = leaky_f(as4.x + adv.x), e1 = leaky_f(as4.y + adv.y);
        float e2 = leaky_f(as4.z + adv.z), e3 = leaky_f(as4.w + adv.w);
        // ---- pass A: max (no exp) ----
        float m[4] = {-FLT_MAX, -FLT_MAX, -FLT_MAX, -FLT_MAX};
        if (lane < total) { m[0] = e0; m[1] = e1; m[2] = e2; m[3] = e3; }
        for (int i = lane + 64; i < total; i += 64) {
            int src = (i < rowlen) ? csr_src[beg + i] : node;
            float4 a4 = *reinterpret_cast<const float4*>(&a_src[(size_t)src * 4]);
            m[0] = fmaxf(m[0], leaky_f(a4.x + adv.x));
            m[1] = fmaxf(m[1], leaky_f(a4.y + adv.y));
            m[2] = fmaxf(m[2], leaky_f(a4.z + adv.z));
            m[3] = fmaxf(m[3], leaky_f(a4.w + adv.w));
        }
        #pragma unroll
        for (int off = 32; off; off >>= 1) {
            #pragma unroll
            for (int h = 0; h < 4; h++) m[h] = fmaxf(m[h], __shfl_xor(m[h], off));
        }
        // ---- pass B: exp once per lane per head, then sum ----
        float ex[4] = {0.f, 0.f, 0.f, 0.f};
        if (lane < total) {
            ex[0] = expf(e0 - m[0]); ex[1] = expf(e1 - m[1]);
            ex[2] = expf(e2 - m[2]); ex[3] = expf(e3 - m[3]);
        }
        float s[4] = {ex[0], ex[1], ex[2], ex[3]};
        for (int i = lane + 64; i < total; i += 64) {
            int src = (i < rowlen) ? csr_src[beg + i] : node;
            float4 a4 = *reinterpret_cast<const float4*>(&a_src[(size_t)src * 4]);
            s[0] += expf(leaky_f(a4.x + adv.x) - m[0]);
            s[1] += expf(leaky_f(a4.y + adv.y) - m[1]);
            s[2] += expf(leaky_f(a4.z + adv.z) - m[2]);
            s[3] += expf(leaky_f(a4.w + adv.w) - m[3]);
        }
        #pragma unroll
        for (int off = 32; off; off >>= 1) {
            #pragma unroll
            for (int h = 0; h < 4; h++) s[h] += __shfl_xor(s[h], off);
        }
        float inv[4];
        #pragma unroll
        for (int h = 0; h < 4; h++) inv[h] = 1.f / (s[h] + 1e-16f);
        // ---- stage chunk-0 {src, alpha} in this wave's LDS slice ----
        src_sh[wv][lane] = sv;
        #pragma unroll
        for (int h = 0; h < 4; h++) al_sh[wv][h][lane] = ex[h] * inv[h];
        __builtin_amdgcn_wave_barrier();
        float acc0 = 0.f, acc1 = 0.f;
        int cnt = min(total, 64);
        for (int i = 0; i < cnt; i++) {
            int src  = src_sh[wv][i];
            float aL = al_sh[wv][hA][i];
            float aH = al_sh[wv][hB][i];
            const float* xr = &xw[(size_t)src * 128];
            acc0 += aL * xr[lane];
            acc1 += aH * xr[64 + lane];
        }
        // rare tail chunks
        for (int base = 64; base < total; base += 64) {
            __builtin_amdgcn_wave_barrier();
            int i = base + lane;
            int src2 = node;
            float a0v = 0.f, a1v = 0.f, a2v = 0.f, a3v = 0.f;
            if (i < total) {
                if (i < rowlen) src2 = csr_src[beg + i];
                float4 a4 = *reinterpret_cast<const float4*>(&a_src[(size_t)src2 * 4]);
                a0v = expf(leaky_f(a4.x + adv.x) - m[0]) * inv[0];
                a1v = expf(leaky_f(a4.y + adv.y) - m[1]) * inv[1];
                a2v = expf(leaky_f(a4.z + adv.z) - m[2]) * inv[2];
                a3v = expf(leaky_f(a4.w + adv.w) - m[3]) * inv[3];
            }
            src_sh[wv][lane] = src2;
            al_sh[wv][0][lane] = a0v; al_sh[wv][1][lane] = a1v;
            al_sh[wv][2][lane] = a2v; al_sh[wv][3][lane] = a3v;
            __builtin_amdgcn_wave_barrier();
            int cnt2 = min(total - base, 64);
            for (int j = 0; j < cnt2; j++) {
                int src  = src_sh[wv][j];
                float aL = al_sh[wv][hA][j];
                float aH = al_sh[wv][hB][j];
                const float* xr = &xw[(size_t)src * 128];
                acc0 += aL * xr[lane];
                acc1 += aH * xr[64 + lane];
            }
        }
        __builtin_amdgcn_wave_barrier();
        int cA = lane, cB = lane + 64;
        float vA = elu_f(acc0 + bias[cA]);
        float vB = elu_f(acc1 + bias[cB]);
        vA = g1[cA] * (vA - mu1[cA]) * rsqrtf(var1[cA] + BN_EPS) + b1[cA];
        vB = g1[cB] * (vB - mu1[cB]) * rsqrtf(var1[cB] + BN_EPS) + b1[cB];
        hout[(size_t)node * 128 + cA] = vA;
        hout[(size_t)node * 128 + cB] = vB;
    }
}

// -------------------------- K7: GCN aggregate — wave/node, weights staged in LDS
__global__ __launch_bounds__(256)
void k_gcn_agg(const int* __restrict__ offsets, const int* __restrict__ csr_src,
               const float* __restrict__ dinv, const float* __restrict__ hw,
               const float* __restrict__ bias,
               const float* __restrict__ g2, const float* __restrict__ b2,
               const float* __restrict__ mu2, const float* __restrict__ var2,
               const float* __restrict__ gateW, const float* __restrict__ gateB,
               float* __restrict__ h2, float* __restrict__ gate, int n) {
    __shared__ int   src_sh[4][64];
    __shared__ float w_sh[4][64];
    int lane = threadIdx.x & 63;
    int wv   = threadIdx.x >> 6;
    int wid  = (blockIdx.x * blockDim.x + threadIdx.x) >> 6;
    int nw   = (gridDim.x * blockDim.x) >> 6;
    for (int node = wid; node < n; node += nw) {
        int beg = offsets[node], end = offsets[node + 1];
        int rowlen = end - beg;
        float dn = dinv[node];
        const float* hr_self = &hw[(size_t)node * 128];
        float acc0 = dn * dn * hr_self[lane];
        float acc1 = dn * dn * hr_self[64 + lane];
        for (int base = 0; base < rowlen; base += 64) {
            __builtin_amdgcn_wave_barrier();
            int i = base + lane;
            int src2 = node;
            float wv2 = 0.f;
            if (i < rowlen) { src2 = csr_src[beg + i]; wv2 = dinv[src2] * dn; }
            src_sh[wv][lane] = src2;
            w_sh[wv][lane]   = wv2;
            __builtin_amdgcn_wave_barrier();
            int cnt = min(rowlen - base, 64);
            for (int j = 0; j < cnt; j++) {
                int src = src_sh[wv][j];
                float w = w_sh[wv][j];
                const float* hr = &hw[(size_t)src * 128];
                acc0 += w * hr[lane];
                acc1 += w * hr[64 + lane];
            }
        }
        __builtin_amdgcn_wave_barrier();
        int cA = lane, cB = lane + 64;
        float vA = elu_f(acc0 + bias[cA]);
        float vB = elu_f(acc1 + bias[cB]);
        vA = g2[cA] * (vA - mu2[cA]) * rsqrtf(var2[cA] + BN_EPS) + b2[cA];
        vB = g2[cB] * (vB - mu2[cB]) * rsqrtf(var2[cB] + BN_EPS) + b2[cB];
        h2[(size_t)node * 128 + cA] = vA;
        h2[(size_t)node * 128 + cB] = vB;
        float p = vA * gateW[cA] + vB * gateW[cB];
        #pragma unroll
        for (int off = 32; off; off >>= 1) p += __shfl_xor(p, off);
        if (lane == 0) gate[node] = p + gateB[0];
    }
}

// -------------------------- K8: GlobalAttention pool, one block per graph
__device__ __forceinline__ int lbound(const int* a, int n, int key) {
    int lo = 0, hi = n;
    while (lo < hi) { int mid = (lo + hi) >> 1; if (a[mid] < key) lo = mid + 1; else hi = mid; }
    return lo;
}

__global__ __launch_bounds__(256)
void k_pool(const int* __restrict__ batch, const float* __restrict__ gate,
            const float* __restrict__ h2, float* __restrict__ grep, int n) {
    int b = blockIdx.x, tid = threadIdx.x;
    __shared__ float red[256];
    __shared__ float sc_sh[256];
    int start = lbound(batch, n, b);
    int end   = lbound(batch, n, b + 1);
    float m = -FLT_MAX;
    for (int i = start + tid; i < end; i += 256) m = fmaxf(m, gate[i]);
    red[tid] = m; __syncthreads();
    for (int s2 = 128; s2 > 0; s2 >>= 1) {
        if (tid < s2) red[tid] = fmaxf(red[tid], red[tid + s2]);
        __syncthreads();
    }
    m = red[0]; __syncthreads();
    float s = 0.f;
    for (int i = start + tid; i < end; i += 256) s += expf(gate[i] - m);
    red[tid] = s; __syncthreads();
    for (int s2 = 128; s2 > 0; s2 >>= 1) {
        if (tid < s2) red[tid] += red[tid + s2];
        __syncthreads();
    }
    float inv = 1.f / (red[0] + 1e-16f);
    __syncthreads();
    int j = tid & 127, half = tid >> 7;
    float acc = 0.f;
    for (int base = start; base < end; base += 256) {
        int cnt = min(256, end - base);
        __syncthreads();
        if (tid < cnt) sc_sh[tid] = expf(gate[base + tid] - m) * inv;
        __syncthreads();
        for (int ii = half; ii < cnt; ii += 2)
            acc += sc_sh[ii] * h2[(size_t)(base + ii) * 128 + j];
    }
    red[tid] = acc; __syncthreads();
    if (half == 0) grep[b * 128 + j] = red[j] + red[128 + j];
}

// -------------------------- K9: LSTM (block per batch elem) + fused final FC
__global__ __launch_bounds__(512, 2)
void k_lstm(const float* __restrict__ quant, const float* __restrict__ Wih,
            const float* __restrict__ Whh, const float* __restrict__ bih,
            const float* __restrict__ bhh, const float* __restrict__ grep,
            const float* __restrict__ fcW, const float* __restrict__ fcB,
            float* __restrict__ out) {
    int b = blockIdx.x, t = threadIdx.x;
    __shared__ __align__(16) float x_sh[KT * KQD];
    __shared__ __align__(16) float h_sh[KLH];
    __shared__ float g_sh[4 * KLH];
    const float4* qrow = reinterpret_cast<const float4*>(&quant[(size_t)b * (KT * KQD)]);
    for (int idx = t; idx < (KT * KQD) / 4; idx += 512)
        reinterpret_cast<float4*>(x_sh)[idx] = qrow[idx];
    float4 wih4[KQD / 4];
    const float4* wihr = reinterpret_cast<const float4*>(&Wih[(size_t)t * KQD]);
    #pragma unroll
    for (int k = 0; k < KQD / 4; k++) wih4[k] = wihr[k];
    float4 whh4[KLH / 4];
    const float4* whhr = reinterpret_cast<const float4*>(&Whh[(size_t)t * KLH]);
    #pragma unroll
    for (int k = 0; k < KLH / 4; k++) whh4[k] = whhr[k];
    float bias = bih[t] + bhh[t];
    float c = 0.f;
    if (t < KLH) h_sh[t] = 0.f;
    __syncthreads();
    for (int step = 0; step < KT; step++) {
        float a0 = 0.f, a1 = 0.f, a2 = 0.f, a3 = 0.f;
        const float4* h4 = reinterpret_cast<const float4*>(h_sh);
        #pragma unroll
        for (int k = 0; k < KLH / 4; k++) {
            float4 hv = h4[k], w = whh4[k];
            a0 += w.x * hv.x; a1 += w.y * hv.y;
            a2 += w.z * hv.z; a3 += w.w * hv.w;
        }
        const float4* x4 = reinterpret_cast<const float4*>(&x_sh[step * KQD]);
        #pragma unroll
        for (int k = 0; k < KQD / 4; k++) {
            float4 xv = x4[k], w = wih4[k];
            a0 += w.x * xv.x; a1 += w.y * xv.y;
            a2 += w.z * xv.z; a3 += w.w * xv.w;
        }
        g_sh[t] = (a0 + a1) + (a2 + a3) + bias;
        __syncthreads();
        if (t < KLH) {
            float ig = sigm_f(g_sh[t]);
            float fg = sigm_f(g_sh[KLH + t]);
            float gg = tanhf(g_sh[2 * KLH + t]);
            float og = sigm_f(g_sh[3 * KLH + t]);
            c = fg * c + ig * gg;
            h_sh[t] = og * tanhf(c);
        }
        __syncthreads();
    }
    if (t < KLH)
        g_sh[t] = fcW[t] * grep[b * 128 + t] + fcW[128 + t] * h_sh[t];
    __syncthreads();
    for (int s2 = 64; s2 > 0; s2 >>= 1) {
        if (t < s2) g_sh[t] += g_sh[t + s2];
        __syncthreads();
    }
    if (t == 0) out[b] = g_sh[0] + fcB[0];
}

// ----------------------------------------------------------------- launcher
extern "C" void kernel_launch(void* const* d_in, const int* in_sizes, int n_in,
                              void* d_out, int out_size, void* d_ws, size_t ws_size,
                              hipStream_t stream) {
    const float* x     = (const float*)d_in[0];
    const int*   ei    = (const int*)  d_in[1];
    const int*   batch = (const int*)  d_in[2];
    const float* quant = (const float*)d_in[3];
    const float* gatW  = (const float*)d_in[4];
    const float* attS  = (const float*)d_in[5];
    const float* attD  = (const float*)d_in[6];
    const float* gatB  = (const float*)d_in[7];
    const float* bn1g  = (const float*)d_in[8];
    const float* bn1b  = (const float*)d_in[9];
    const float* bn1m  = (const float*)d_in[10];
    const float* bn1v  = (const float*)d_in[11];
    const float* gcnW  = (const float*)d_in[12];
    const float* gcnB  = (const float*)d_in[13];
    const float* bn2g  = (const float*)d_in[14];
    const float* bn2b  = (const float*)d_in[15];
    const float* bn2m  = (const float*)d_in[16];
    const float* bn2v  = (const float*)d_in[17];
    const float* gateW = (const float*)d_in[18];
    const float* gateB = (const float*)d_in[19];
    const float* Wih   = (const float*)d_in[20];
    const float* Whh   = (const float*)d_in[21];
    const float* bih   = (const float*)d_in[22];
    const float* bhh   = (const float*)d_in[23];
    const float* fcW   = (const float*)d_in[24];
    const float* fcB   = (const float*)d_in[25];

    int N = in_sizes[0] / KIN;
    int E = in_sizes[1] / 2;
    int B = in_sizes[3] / (KT * KQD);

    char* ws = (char*)d_ws;
    size_t off = 0;
    auto alloc = [&](size_t bytes) -> void* {
        void* p = ws + off;
        off += (bytes + 511) & ~(size_t)511;
        return p;
    };
    int*   deg     = (int*)  alloc((size_t)N * 4);
    int*   offsets = (int*)  alloc((size_t)(N + 1) * 4);
    int*   cursor  = (int*)  alloc((size_t)N * 4);
    float* dinv    = (float*)alloc((size_t)N * 4);
    int*   csr_src = (int*)  alloc((size_t)E * 4);
    float* a_src   = (float*)alloc((size_t)N * 16);
    float* a_dst   = (float*)alloc((size_t)N * 16);
    float* xw      = (float*)alloc((size_t)N * 512);   // xw, then reused as hw
    float* hbuf    = (float*)alloc((size_t)N * 512);   // h_bn, then reused as h2
    float* gate    = (float*)alloc((size_t)N * 4);
    float* grep    = (float*)alloc((size_t)B * 512);

    hipMemsetAsync(deg, 0, (size_t)N * 4, stream);
    int eb = (E + 255) / 256;
    k_deg <<<eb, 256, 0, stream>>>(ei, E, deg);
    k_scan<<<1, 1024, 0, stream>>>(deg, N, offsets, cursor, dinv);
    k_fill<<<eb, 256, 0, stream>>>(ei, E, cursor, csr_src);

    k_gemm128<true ><<<768, 512, 0, stream>>>(x, gatW, xw, N, attS, attD, a_src, a_dst);
    k_gat_agg<<<2048, 256, 0, stream>>>(offsets, csr_src, a_src, a_dst, xw, gatB,
                                        bn1g, bn1b, bn1m, bn1v, hbuf, N);
    k_gemm128<false><<<768, 512, 0, stream>>>(hbuf, gcnW, xw, N,
                                              nullptr, nullptr, nullptr, nullptr);
    k_gcn_agg<<<2048, 256, 0, stream>>>(offsets, csr_src, dinv, xw, gcnB,
                                        bn2g, bn2b, bn2m, bn2v, gateW, gateB,
                                        hbuf, gate, N);
    k_pool<<<B, 256, 0, stream>>>(batch, gate, hbuf, grep, N);
    k_lstm<<<B, 512, 0, stream>>>(quant, Wih, Whh, bih, bhh, grep, fcW, fcB,
                                  (float*)d_out);
}

// Round 3
// 550.743 us; speedup vs baseline: 1.2159x; 1.0637x over previous
//
#include <hip/hip_runtime.h>
#include <cfloat>
#include <cstddef>

constexpr int KIN   = 128;
constexpr int KQD   = 32;
constexpr int KT    = 50;
constexpr int KLH   = 128;
constexpr float BN_EPS = 1e-5f;

__device__ __forceinline__ float elu_f(float x)  { return x > 0.f ? x : expm1f(x); }
__device__ __forceinline__ float sigm_f(float x) { return 1.f / (1.f + expf(-x)); }
__device__ __forceinline__ float leaky_f(float x){ return x > 0.f ? x : 0.2f * x; }

// pack two f32 into two bf16 (RNE) in one uint: lo in [15:0], hi in [31:16]
__device__ __forceinline__ unsigned bfpack(float lo, float hi) {
    unsigned ul = __float_as_uint(lo), uh = __float_as_uint(hi);
    ul += 0x7FFFu + ((ul >> 16) & 1u);
    uh += 0x7FFFu + ((uh >> 16) & 1u);
    return (ul >> 16) | (uh & 0xFFFF0000u);
}
__device__ __forceinline__ float bflo(unsigned u) { return __uint_as_float(u << 16); }
__device__ __forceinline__ float bfhi(unsigned u) { return __uint_as_float(u & 0xFFFF0000u); }
__device__ __forceinline__ float rdlane(float v, int k) {
    return __int_as_float(__builtin_amdgcn_readlane(__float_as_int(v), k));
}

// ---------------------------------------------------------------- K1: degree
__global__ void k_deg(const int* __restrict__ ei, int E, int* __restrict__ deg) {
    int e = blockIdx.x * blockDim.x + threadIdx.x;
    if (e < E) atomicAdd(&deg[ei[E + e]], 1);
}

// ------------------------------------------------- K2: exclusive scan (1 blk)
__global__ __launch_bounds__(1024)
void k_scan(const int* __restrict__ deg, int n, int* __restrict__ offsets,
            int* __restrict__ cursor, float* __restrict__ dinv) {
    __shared__ int wsum[16];
    __shared__ int carry_sh;
    int tid = threadIdx.x, lane = tid & 63, w = tid >> 6;
    if (tid == 0) { carry_sh = 0; offsets[0] = 0; }
    __syncthreads();
    for (int base = 0; base < n; base += 4096) {
        int i0 = base + tid * 4;
        int v[4];
        #pragma unroll
        for (int j = 0; j < 4; j++) v[j] = (i0 + j < n) ? deg[i0 + j] : 0;
        int tsum = v[0] + v[1] + v[2] + v[3];
        int sc = tsum;
        #pragma unroll
        for (int d = 1; d < 64; d <<= 1) {
            int o = __shfl_up(sc, d);
            if (lane >= d) sc += o;
        }
        __syncthreads();
        if (lane == 63) wsum[w] = sc;
        __syncthreads();
        if (w == 0) {
            int xx = (lane < 16) ? wsum[lane] : 0;
            #pragma unroll
            for (int d = 1; d < 16; d <<= 1) {
                int o = __shfl_up(xx, d);
                if (lane >= d) xx += o;
            }
            if (lane < 16) wsum[lane] = xx;
        }
        __syncthreads();
        int carry = carry_sh;
        int woff  = (w > 0) ? wsum[w - 1] : 0;
        int run   = carry + woff + sc - tsum;
        #pragma unroll
        for (int j = 0; j < 4; j++) {
            int i = i0 + j;
            if (i < n) {
                cursor[i]      = run;
                offsets[i + 1] = run + v[j];
                dinv[i]        = rsqrtf((float)(v[j] + 1));
                run += v[j];
            }
        }
        __syncthreads();
        if (tid == 0) carry_sh = carry + wsum[15];
    }
}

// ---------------------------------------------------------------- K3: fill
__global__ void k_fill(const int* __restrict__ ei, int E, int* __restrict__ cursor,
                       int* __restrict__ csr_src) {
    int e = blockIdx.x * blockDim.x + threadIdx.x;
    if (e < E) {
        int s = ei[e], d = ei[E + e];
        int pos = atomicAdd(&cursor[d], 1);
        csr_src[pos] = s;
    }
}

// --------------- K4/K6: 128x128 GEMM, W in LDS; output packed bf16 pairs
template <bool ATT>
__global__ __launch_bounds__(512)
void k_gemm128(const float* __restrict__ X, const float* __restrict__ W,
               unsigned* __restrict__ Yb, int nrows,
               const float* __restrict__ attS, const float* __restrict__ attD,
               float* __restrict__ a_src, float* __restrict__ a_dst) {
    __shared__ float w_sh[64 * 128];
    __shared__ float x_sh[32 * 129];
    __shared__ float as_sh[128], ad_sh[128];
    int tid = threadIdx.x;
    if (ATT && tid < 128) { as_sh[tid] = attS[tid]; ad_sh[tid] = attD[tid]; }
    int row_l = tid >> 4;
    int cg    = tid & 15;
    int c0    = cg * 8;
    int nch = (nrows + 31) / 32;
    for (int ch = blockIdx.x; ch < nch; ch += gridDim.x) {
        int r0 = ch * 32;
        __syncthreads();
        for (int idx = tid; idx < 32 * 128; idx += 512) {
            int rr = idx >> 7, cc = idx & 127;
            int gr = r0 + rr;
            x_sh[rr * 129 + cc] = (gr < nrows) ? X[(size_t)gr * 128 + cc] : 0.f;
        }
        float acc[8];
        #pragma unroll
        for (int i = 0; i < 8; i++) acc[i] = 0.f;
        #pragma unroll
        for (int kh = 0; kh < 2; kh++) {
            __syncthreads();
            for (int idx = tid; idx < 64 * 128; idx += 512)
                w_sh[idx] = W[kh * 64 * 128 + idx];
            __syncthreads();
            const float* xr = &x_sh[row_l * 129 + kh * 64];
            #pragma unroll 4
            for (int k = 0; k < 64; k++) {
                float xv = xr[k];
                float4 w0 = *reinterpret_cast<const float4*>(&w_sh[k * 128 + c0]);
                float4 w1 = *reinterpret_cast<const float4*>(&w_sh[k * 128 + c0 + 4]);
                acc[0] += xv * w0.x; acc[1] += xv * w0.y;
                acc[2] += xv * w0.z; acc[3] += xv * w0.w;
                acc[4] += xv * w1.x; acc[5] += xv * w1.y;
                acc[6] += xv * w1.z; acc[7] += xv * w1.w;
            }
        }
        int r = r0 + row_l;
        if (r < nrows) {
            uint4 pk;
            pk.x = bfpack(acc[0], acc[1]);
            pk.y = bfpack(acc[2], acc[3]);
            pk.z = bfpack(acc[4], acc[5]);
            pk.w = bfpack(acc[6], acc[7]);
            *reinterpret_cast<uint4*>(&Yb[(size_t)r * 64 + cg * 4]) = pk;
            if (ATT) {
                float ps = 0.f, pd = 0.f;
                #pragma unroll
                for (int i = 0; i < 8; i++) {
                    ps += acc[i] * as_sh[c0 + i];
                    pd += acc[i] * ad_sh[c0 + i];
                }
                ps += __shfl_xor(ps, 1); ps += __shfl_xor(ps, 2);
                pd += __shfl_xor(pd, 1); pd += __shfl_xor(pd, 2);
                if ((cg & 3) == 0) {
                    int h = cg >> 2;
                    a_src[r * 4 + h] = ps;
                    a_dst[r * 4 + h] = pd;
                }
            }
        }
    }
}

// ---------- K5: GAT aggregate — wave/node, alpha in LDS, bf16-pair gather
__global__ __launch_bounds__(256)
void k_gat_agg(const int* __restrict__ offsets, const int* __restrict__ csr_src,
               const float* __restrict__ a_src, const float* __restrict__ a_dst,
               const unsigned* __restrict__ xwb, const float* __restrict__ bias,
               const float* __restrict__ g1, const float* __restrict__ b1,
               const float* __restrict__ mu1, const float* __restrict__ var1,
               float* __restrict__ hout, int n) {
    __shared__ int   src_sh[4][64];
    __shared__ float al_sh[4][4][64];     // [wave][head][edge]
    int lane = threadIdx.x & 63;
    int wv   = threadIdx.x >> 6;
    int wid  = (blockIdx.x * blockDim.x + threadIdx.x) >> 6;
    int nw   = (gridDim.x * blockDim.x) >> 6;
    int hP   = lane >> 4;                 // head of cols (2l, 2l+1)
    int c0 = lane * 2, c1 = c0 + 1;
    // hoisted epilogue params
    float bi0 = bias[c0], bi1 = bias[c1];
    float A0 = g1[c0] * rsqrtf(var1[c0] + BN_EPS);
    float A1 = g1[c1] * rsqrtf(var1[c1] + BN_EPS);
    float B0 = b1[c0] - mu1[c0] * A0;
    float B1 = b1[c1] - mu1[c1] * A1;
    for (int node = wid; node < n; node += nw) {
        int beg = offsets[node], end = offsets[node + 1];
        int rowlen = end - beg, total = rowlen + 1;   // + self loop
        float4 adv = *reinterpret_cast<const float4*>(&a_dst[(size_t)node * 4]);
        int sv = (lane < rowlen) ? csr_src[beg + lane] : node;
        float4 as4 = *reinterpret_cast<const float4*>(&a_src[(size_t)sv * 4]);
        float e0 = leaky_f(as4.x + adv.x), e1 = leaky_f(as4.y + adv.y);
        float e2 = leaky_f(as4.z + adv.z), e3 = leaky_f(as4.w + adv.w);
        // pass A: max
        float m[4] = {-FLT_MAX, -FLT_MAX, -FLT_MAX, -FLT_MAX};
        if (lane < total) { m[0] = e0; m[1] = e1; m[2] = e2; m[3] = e3; }
        for (int i = lane + 64; i < total; i += 64) {
            int src = (i < rowlen) ? csr_src[beg + i] : node;
            float4 a4 = *reinterpret_cast<const float4*>(&a_src[(size_t)src * 4]);
            m[0] = fmaxf(m[0], leaky_f(a4.x + adv.x));
            m[1] = fmaxf(m[1], leaky_f(a4.y + adv.y));
            m[2] = fmaxf(m[2], leaky_f(a4.z + adv.z));
            m[3] = fmaxf(m[3], leaky_f(a4.w + adv.w));
        }
        #pragma unroll
        for (int off = 32; off; off >>= 1) {
            #pragma unroll
            for (int h = 0; h < 4; h++) m[h] = fmaxf(m[h], __shfl_xor(m[h], off));
        }
        // pass B: exp + sum
        float ex[4] = {0.f, 0.f, 0.f, 0.f};
        if (lane < total) {
            ex[0] = expf(e0 - m[0]); ex[1] = expf(e1 - m[1]);
            ex[2] = expf(e2 - m[2]); ex[3] = expf(e3 - m[3]);
        }
        float s[4] = {ex[0], ex[1], ex[2], ex[3]};
        for (int i = lane + 64; i < total; i += 64) {
            int src = (i < rowlen) ? csr_src[beg + i] : node;
            float4 a4 = *reinterpret_cast<const float4*>(&a_src[(size_t)src * 4]);
            s[0] += expf(leaky_f(a4.x + adv.x) - m[0]);
            s[1] += expf(leaky_f(a4.y + adv.y) - m[1]);
            s[2] += expf(leaky_f(a4.z + adv.z) - m[2]);
            s[3] += expf(leaky_f(a4.w + adv.w) - m[3]);
        }
        #pragma unroll
        for (int off = 32; off; off >>= 1) {
            #pragma unroll
            for (int h = 0; h < 4; h++) s[h] += __shfl_xor(s[h], off);
        }
        float inv[4];
        #pragma unroll
        for (int h = 0; h < 4; h++) inv[h] = 1.f / (s[h] + 1e-16f);
        // stage chunk-0 {src, alpha}
        src_sh[wv][lane] = sv;
        #pragma unroll
        for (int h = 0; h < 4; h++) al_sh[wv][h][lane] = ex[h] * inv[h];
        __builtin_amdgcn_wave_barrier();
        float acc0 = 0.f, acc1 = 0.f;
        int cnt = min(total, 64);
        for (int i = 0; i < cnt; i++) {
            int src  = src_sh[wv][i];
            float aP = al_sh[wv][hP][i];
            unsigned u = xwb[(size_t)src * 64 + lane];
            acc0 += aP * bflo(u);
            acc1 += aP * bfhi(u);
        }
        for (int base = 64; base < total; base += 64) {
            __builtin_amdgcn_wave_barrier();
            int i = base + lane;
            int src2 = node;
            float a0v = 0.f, a1v = 0.f, a2v = 0.f, a3v = 0.f;
            if (i < total) {
                if (i < rowlen) src2 = csr_src[beg + i];
                float4 a4 = *reinterpret_cast<const float4*>(&a_src[(size_t)src2 * 4]);
                a0v = expf(leaky_f(a4.x + adv.x) - m[0]) * inv[0];
                a1v = expf(leaky_f(a4.y + adv.y) - m[1]) * inv[1];
                a2v = expf(leaky_f(a4.z + adv.z) - m[2]) * inv[2];
                a3v = expf(leaky_f(a4.w + adv.w) - m[3]) * inv[3];
            }
            src_sh[wv][lane] = src2;
            al_sh[wv][0][lane] = a0v; al_sh[wv][1][lane] = a1v;
            al_sh[wv][2][lane] = a2v; al_sh[wv][3][lane] = a3v;
            __builtin_amdgcn_wave_barrier();
            int cnt2 = min(total - base, 64);
            for (int j = 0; j < cnt2; j++) {
                int src  = src_sh[wv][j];
                float aP = al_sh[wv][hP][j];
                unsigned u = xwb[(size_t)src * 64 + lane];
                acc0 += aP * bflo(u);
                acc1 += aP * bfhi(u);
            }
        }
        __builtin_amdgcn_wave_barrier();
        float vA = elu_f(acc0 + bi0);
        float vB = elu_f(acc1 + bi1);
        vA = vA * A0 + B0;
        vB = vB * A1 + B1;
        *reinterpret_cast<float2*>(&hout[(size_t)node * 128 + c0]) =
            make_float2(vA, vB);
    }
}

// ---------- K7: GCN aggregate — wave/node, bf16-pair gather + gate dot
__global__ __launch_bounds__(256)
void k_gcn_agg(const int* __restrict__ offsets, const int* __restrict__ csr_src,
               const float* __restrict__ dinv, const unsigned* __restrict__ hwb,
               const float* __restrict__ bias,
               const float* __restrict__ g2, const float* __restrict__ b2,
               const float* __restrict__ mu2, const float* __restrict__ var2,
               const float* __restrict__ gateW, const float* __restrict__ gateB,
               float* __restrict__ h2, float* __restrict__ gate, int n) {
    __shared__ int   src_sh[4][64];
    __shared__ float w_sh[4][64];
    int lane = threadIdx.x & 63;
    int wv   = threadIdx.x >> 6;
    int wid  = (blockIdx.x * blockDim.x + threadIdx.x) >> 6;
    int nw   = (gridDim.x * blockDim.x) >> 6;
    int c0 = lane * 2, c1 = c0 + 1;
    float bi0 = bias[c0], bi1 = bias[c1];
    float A0 = g2[c0] * rsqrtf(var2[c0] + BN_EPS);
    float A1 = g2[c1] * rsqrtf(var2[c1] + BN_EPS);
    float B0 = b2[c0] - mu2[c0] * A0;
    float B1 = b2[c1] - mu2[c1] * A1;
    float gw0 = gateW[c0], gw1 = gateW[c1], gB = gateB[0];
    for (int node = wid; node < n; node += nw) {
        int beg = offsets[node], end = offsets[node + 1];
        int rowlen = end - beg;
        float dn = dinv[node];
        unsigned us = hwb[(size_t)node * 64 + lane];
        float acc0 = dn * dn * bflo(us);
        float acc1 = dn * dn * bfhi(us);
        for (int base = 0; base < rowlen; base += 64) {
            __builtin_amdgcn_wave_barrier();
            int i = base + lane;
            int src2 = node;
            float wv2 = 0.f;
            if (i < rowlen) { src2 = csr_src[beg + i]; wv2 = dinv[src2] * dn; }
            src_sh[wv][lane] = src2;
            w_sh[wv][lane]   = wv2;
            __builtin_amdgcn_wave_barrier();
            int cnt = min(rowlen - base, 64);
            for (int j = 0; j < cnt; j++) {
                int src = src_sh[wv][j];
                float w = w_sh[wv][j];
                unsigned u = hwb[(size_t)src * 64 + lane];
                acc0 += w * bflo(u);
                acc1 += w * bfhi(u);
            }
        }
        __builtin_amdgcn_wave_barrier();
        float vA = elu_f(acc0 + bi0);
        float vB = elu_f(acc1 + bi1);
        vA = vA * A0 + B0;
        vB = vB * A1 + B1;
        *reinterpret_cast<float2*>(&h2[(size_t)node * 128 + c0]) =
            make_float2(vA, vB);
        float p = vA * gw0 + vB * gw1;
        #pragma unroll
        for (int off = 32; off; off >>= 1) p += __shfl_xor(p, off);
        if (lane == 0) gate[node] = p + gB;
    }
}

// -------------------------- K8: GlobalAttention pool, one block per graph
__device__ __forceinline__ int lbound(const int* a, int n, int key) {
    int lo = 0, hi = n;
    while (lo < hi) { int mid = (lo + hi) >> 1; if (a[mid] < key) lo = mid + 1; else hi = mid; }
    return lo;
}

__global__ __launch_bounds__(256)
void k_pool(const int* __restrict__ batch, const float* __restrict__ gate,
            const float* __restrict__ h2, float* __restrict__ grep, int n) {
    int b = blockIdx.x, tid = threadIdx.x;
    __shared__ float red[256];
    __shared__ float sc_sh[256];
    int start = lbound(batch, n, b);
    int end   = lbound(batch, n, b + 1);
    float m = -FLT_MAX;
    for (int i = start + tid; i < end; i += 256) m = fmaxf(m, gate[i]);
    red[tid] = m; __syncthreads();
    for (int s2 = 128; s2 > 0; s2 >>= 1) {
        if (tid < s2) red[tid] = fmaxf(red[tid], red[tid + s2]);
        __syncthreads();
    }
    m = red[0]; __syncthreads();
    float s = 0.f;
    for (int i = start + tid; i < end; i += 256) s += expf(gate[i] - m);
    red[tid] = s; __syncthreads();
    for (int s2 = 128; s2 > 0; s2 >>= 1) {
        if (tid < s2) red[tid] += red[tid + s2];
        __syncthreads();
    }
    float inv = 1.f / (red[0] + 1e-16f);
    __syncthreads();
    int j = tid & 127, half = tid >> 7;
    float acc = 0.f;
    for (int base = start; base < end; base += 256) {
        int cnt = min(256, end - base);
        __syncthreads();
        if (tid < cnt) sc_sh[tid] = expf(gate[base + tid] - m) * inv;
        __syncthreads();
        for (int ii = half; ii < cnt; ii += 2)
            acc += sc_sh[ii] * h2[(size_t)(base + ii) * 128 + j];
    }
    red[tid] = acc; __syncthreads();
    if (half == 0) grep[b * 128 + j] = red[j] + red[128 + j];
}

// ---- K9: LSTM — readlane h-broadcast, SGPR x, weights VGPR-resident (k-split)
__global__ __launch_bounds__(1024, 4)
void k_lstm(const float* __restrict__ quant, const float* __restrict__ Wih,
            const float* __restrict__ Whh, const float* __restrict__ bih,
            const float* __restrict__ bhh, const float* __restrict__ grep,
            const float* __restrict__ fcW, const float* __restrict__ fcB,
            float* __restrict__ out) {
    int b = blockIdx.x, t = threadIdx.x;
    int g = t & 511, half = t >> 9, lane = t & 63;
    __shared__ float h_sh[KLH];
    __shared__ float gp_sh[2 * 512];
    __shared__ float red[KLH];
    float whh[64], wih[16];
    #pragma unroll
    for (int k = 0; k < 64; k++) whh[k] = Whh[(size_t)g * KLH + half * 64 + k];
    #pragma unroll
    for (int k = 0; k < 16; k++) wih[k] = Wih[(size_t)g * KQD + half * 16 + k];
    float bias = (half == 0) ? (bih[g] + bhh[g]) : 0.f;
    const float* xb = &quant[(size_t)b * (KT * KQD)];
    float c = 0.f;
    if (t < KLH) h_sh[t] = 0.f;
    __syncthreads();
    for (int step = 0; step < KT; step++) {
        float hreg = h_sh[half * 64 + lane];      // wave holds its k-half of h
        float a = bias;
        #pragma unroll
        for (int k = 0; k < 64; k++)
            a += rdlane(hreg, k) * whh[k];         // SGPR-broadcast FMA
        const float* xs = xb + step * KQD + half * 16;   // uniform -> s_load
        #pragma unroll
        for (int k = 0; k < 16; k++) a += xs[k] * wih[k];
        gp_sh[half * 512 + g] = a;
        __syncthreads();
        if (t < KLH) {
            float ig = sigm_f(gp_sh[t]       + gp_sh[512 + t]);
            float fg = sigm_f(gp_sh[128 + t] + gp_sh[640 + t]);
            float gg = tanhf (gp_sh[256 + t] + gp_sh[768 + t]);
            float og = sigm_f(gp_sh[384 + t] + gp_sh[896 + t]);
            c = fg * c + ig * gg;
            h_sh[t] = og * tanhf(c);
        }
        __syncthreads();
    }
    if (t < KLH)
        red[t] = fcW[t] * grep[b * 128 + t] + fcW[128 + t] * h_sh[t];
    __syncthreads();
    for (int s2 = 64; s2 > 0; s2 >>= 1) {
        if (t < s2) red[t] += red[t + s2];
        __syncthreads();
    }
    if (t == 0) out[b] = red[0] + fcB[0];
}

// ----------------------------------------------------------------- launcher
extern "C" void kernel_launch(void* const* d_in, const int* in_sizes, int n_in,
                              void* d_out, int out_size, void* d_ws, size_t ws_size,
                              hipStream_t stream) {
    const float* x     = (const float*)d_in[0];
    const int*   ei    = (const int*)  d_in[1];
    const int*   batch = (const int*)  d_in[2];
    const float* quant = (const float*)d_in[3];
    const float* gatW  = (const float*)d_in[4];
    const float* attS  = (const float*)d_in[5];
    const float* attD  = (const float*)d_in[6];
    const float* gatB  = (const float*)d_in[7];
    const float* bn1g  = (const float*)d_in[8];
    const float* bn1b  = (const float*)d_in[9];
    const float* bn1m  = (const float*)d_in[10];
    const float* bn1v  = (const float*)d_in[11];
    const float* gcnW  = (const float*)d_in[12];
    const float* gcnB  = (const float*)d_in[13];
    const float* bn2g  = (const float*)d_in[14];
    const float* bn2b  = (const float*)d_in[15];
    const float* bn2m  = (const float*)d_in[16];
    const float* bn2v  = (const float*)d_in[17];
    const float* gateW = (const float*)d_in[18];
    const float* gateB = (const float*)d_in[19];
    const float* Wih   = (const float*)d_in[20];
    const float* Whh   = (const float*)d_in[21];
    const float* bih   = (const float*)d_in[22];
    const float* bhh   = (const float*)d_in[23];
    const float* fcW   = (const float*)d_in[24];
    const float* fcB   = (const float*)d_in[25];

    int N = in_sizes[0] / KIN;
    int E = in_sizes[1] / 2;
    int B = in_sizes[3] / (KT * KQD);

    char* ws = (char*)d_ws;
    size_t off = 0;
    auto alloc = [&](size_t bytes) -> void* {
        void* p = ws + off;
        off += (bytes + 511) & ~(size_t)511;
        return p;
    };
    int*      deg     = (int*)     alloc((size_t)N * 4);
    int*      offsets = (int*)     alloc((size_t)(N + 1) * 4);
    int*      cursor  = (int*)     alloc((size_t)N * 4);
    float*    dinv    = (float*)   alloc((size_t)N * 4);
    int*      csr_src = (int*)     alloc((size_t)E * 4);
    float*    a_src   = (float*)   alloc((size_t)N * 16);
    float*    a_dst   = (float*)   alloc((size_t)N * 16);
    unsigned* xwb     = (unsigned*)alloc((size_t)N * 256);  // bf16 gemm1 out; reused as hwb
    float*    hbuf    = (float*)   alloc((size_t)N * 512);  // f32 gat out; reused as h2
    float*    gate    = (float*)   alloc((size_t)N * 4);
    float*    grep    = (float*)   alloc((size_t)B * 512);

    hipMemsetAsync(deg, 0, (size_t)N * 4, stream);
    int eb = (E + 255) / 256;
    k_deg <<<eb, 256, 0, stream>>>(ei, E, deg);
    k_scan<<<1, 1024, 0, stream>>>(deg, N, offsets, cursor, dinv);
    k_fill<<<eb, 256, 0, stream>>>(ei, E, cursor, csr_src);

    k_gemm128<true ><<<768, 512, 0, stream>>>(x, gatW, xwb, N, attS, attD, a_src, a_dst);
    k_gat_agg<<<2048, 256, 0, stream>>>(offsets, csr_src, a_src, a_dst, xwb, gatB,
                                        bn1g, bn1b, bn1m, bn1v, hbuf, N);
    k_gemm128<false><<<768, 512, 0, stream>>>(hbuf, gcnW, xwb, N,
                                              nullptr, nullptr, nullptr, nullptr);
    k_gcn_agg<<<2048, 256, 0, stream>>>(offsets, csr_src, dinv, xwb, gcnB,
                                        bn2g, bn2b, bn2m, bn2v, gateW, gateB,
                                        hbuf, gate, N);
    k_pool<<<B, 256, 0, stream>>>(batch, gate, hbuf, grep, N);
    k_lstm<<<B, 1024, 0, stream>>>(quant, Wih, Whh, bih, bhh, grep, fcW, fcB,
                                   (float*)d_out);
}

// Round 4
// 494.747 us; speedup vs baseline: 1.3535x; 1.1132x over previous
//
#include <hip/hip_runtime.h>
#include <cfloat>
#include <cstddef>

constexpr int KIN   = 128;
constexpr int KQD   = 32;
constexpr int KT    = 50;
constexpr int KLH   = 128;
constexpr float BN_EPS = 1e-5f;

typedef __attribute__((ext_vector_type(8))) short bf16x8;
typedef __attribute__((ext_vector_type(4))) float f32x4;
union U8 { bf16x8 v; unsigned u[4]; };

__device__ __forceinline__ float elu_f(float x)  { return x > 0.f ? x : expm1f(x); }
__device__ __forceinline__ float sigm_f(float x) { return 1.f / (1.f + expf(-x)); }
__device__ __forceinline__ float leaky_f(float x){ return x > 0.f ? x : 0.2f * x; }

__device__ __forceinline__ unsigned bfpack(float lo, float hi) {
    unsigned ul = __float_as_uint(lo), uh = __float_as_uint(hi);
    ul += 0x7FFFu + ((ul >> 16) & 1u);
    uh += 0x7FFFu + ((uh >> 16) & 1u);
    return (ul >> 16) | (uh & 0xFFFF0000u);
}
__device__ __forceinline__ float bflo(unsigned u) { return __uint_as_float(u << 16); }
__device__ __forceinline__ float bfhi(unsigned u) { return __uint_as_float(u & 0xFFFF0000u); }
__device__ __forceinline__ float rdlane(float v, int k) {
    return __int_as_float(__builtin_amdgcn_readlane(__float_as_int(v), k));
}

// ---------------------------------------------------------------- K1: degree
__global__ void k_deg(const int* __restrict__ ei, int E, int* __restrict__ deg) {
    int e = blockIdx.x * blockDim.x + threadIdx.x;
    if (e < E) atomicAdd(&deg[ei[E + e]], 1);
}

// ------------------------------------------------- K2: exclusive scan (1 blk)
__global__ __launch_bounds__(1024)
void k_scan(const int* __restrict__ deg, int n, int* __restrict__ offsets,
            int* __restrict__ cursor, float* __restrict__ dinv) {
    __shared__ int wsum[16];
    __shared__ int carry_sh;
    int tid = threadIdx.x, lane = tid & 63, w = tid >> 6;
    if (tid == 0) { carry_sh = 0; offsets[0] = 0; }
    __syncthreads();
    for (int base = 0; base < n; base += 4096) {
        int i0 = base + tid * 4;
        int v[4];
        #pragma unroll
        for (int j = 0; j < 4; j++) v[j] = (i0 + j < n) ? deg[i0 + j] : 0;
        int tsum = v[0] + v[1] + v[2] + v[3];
        int sc = tsum;
        #pragma unroll
        for (int d = 1; d < 64; d <<= 1) {
            int o = __shfl_up(sc, d);
            if (lane >= d) sc += o;
        }
        __syncthreads();
        if (lane == 63) wsum[w] = sc;
        __syncthreads();
        if (w == 0) {
            int xx = (lane < 16) ? wsum[lane] : 0;
            #pragma unroll
            for (int d = 1; d < 16; d <<= 1) {
                int o = __shfl_up(xx, d);
                if (lane >= d) xx += o;
            }
            if (lane < 16) wsum[lane] = xx;
        }
        __syncthreads();
        int carry = carry_sh;
        int woff  = (w > 0) ? wsum[w - 1] : 0;
        int run   = carry + woff + sc - tsum;
        #pragma unroll
        for (int j = 0; j < 4; j++) {
            int i = i0 + j;
            if (i < n) {
                cursor[i]      = run;
                offsets[i + 1] = run + v[j];
                dinv[i]        = rsqrtf((float)(v[j] + 1));
                run += v[j];
            }
        }
        __syncthreads();
        if (tid == 0) carry_sh = carry + wsum[15];
    }
}

// ---------------------------------------------------------------- K3: fill
__global__ void k_fill(const int* __restrict__ ei, int E, int* __restrict__ cursor,
                       int* __restrict__ csr_src) {
    int e = blockIdx.x * blockDim.x + threadIdx.x;
    if (e < E) {
        int s = ei[e], d = ei[E + e];
        int pos = atomicAdd(&cursor[d], 1);
        csr_src[pos] = s;
    }
}

// ------------- K4/K6: MFMA bf16 GEMM  Y[r,:] = X[r,:] @ W,  128x128 weights
// Block: 256 thr = 4 waves; all waves share one 16-row chunk; wave wv owns
// cols [wv*32, wv*32+32). W^T fragments preloaded in VGPRs.
template <bool ATT>
__global__ __launch_bounds__(256, 4)
void k_gemm_mfma(const float* __restrict__ X, const float* __restrict__ W,
                 unsigned* __restrict__ Yb, int nrows,
                 const float* __restrict__ attS, const float* __restrict__ attD,
                 float* __restrict__ a_src, float* __restrict__ a_dst) {
    __shared__ float tile[16][132];
    __shared__ float as_sh[128], ad_sh[128];
    int tid  = threadIdx.x;
    int lane = tid & 63;
    int wv   = tid >> 6;
    if (ATT && tid < 128) { as_sh[tid] = attS[tid]; ad_sh[tid] = attD[tid]; }
    int l16 = lane & 15;          // row (A) / col-in-tile (B,D)
    int kq  = (lane >> 4) * 8;    // k sub-offset
    // ---- preload B = W^T fragments: bfr[nt][kk], col = wv*32 + nt*16 + l16
    bf16x8 bfr[2][4];
    #pragma unroll
    for (int nt = 0; nt < 2; nt++) {
        int n = wv * 32 + nt * 16 + l16;
        #pragma unroll
        for (int kk = 0; kk < 4; kk++) {
            int k0 = kk * 32 + kq;
            float f[8];
            #pragma unroll
            for (int j = 0; j < 8; j++) f[j] = W[(size_t)(k0 + j) * 128 + n];
            U8 t;
            t.u[0] = bfpack(f[0], f[1]); t.u[1] = bfpack(f[2], f[3]);
            t.u[2] = bfpack(f[4], f[5]); t.u[3] = bfpack(f[6], f[7]);
            bfr[nt][kk] = t.v;
        }
    }
    int nch = (nrows + 15) / 16;
    for (int ch = blockIdx.x; ch < nch; ch += gridDim.x) {
        int r0 = ch * 16;
        int r  = r0 + l16;
        bool rok = r < nrows;
        const float* xr = X + (size_t)r * 128 + kq;
        float4 z4 = make_float4(0.f, 0.f, 0.f, 0.f);
        bf16x8 afr[4];
        #pragma unroll
        for (int kk = 0; kk < 4; kk++) {
            float4 p = rok ? *reinterpret_cast<const float4*>(xr + kk * 32)     : z4;
            float4 q = rok ? *reinterpret_cast<const float4*>(xr + kk * 32 + 4) : z4;
            U8 t;
            t.u[0] = bfpack(p.x, p.y); t.u[1] = bfpack(p.z, p.w);
            t.u[2] = bfpack(q.x, q.y); t.u[3] = bfpack(q.z, q.w);
            afr[kk] = t.v;
        }
        f32x4 acc0 = {0.f, 0.f, 0.f, 0.f};
        f32x4 acc1 = {0.f, 0.f, 0.f, 0.f};
        #pragma unroll
        for (int kk = 0; kk < 4; kk++) {
            acc0 = __builtin_amdgcn_mfma_f32_16x16x32_bf16(afr[kk], bfr[0][kk], acc0, 0, 0, 0);
            acc1 = __builtin_amdgcn_mfma_f32_16x16x32_bf16(afr[kk], bfr[1][kk], acc1, 0, 0, 0);
        }
        __syncthreads();              // previous chunk's readers done
        int rowb = (lane >> 4) * 4;
        int cb   = wv * 32 + l16;
        #pragma unroll
        for (int reg = 0; reg < 4; reg++) {
            tile[rowb + reg][cb]      = acc0[reg];
            tile[rowb + reg][cb + 16] = acc1[reg];
        }
        __syncthreads();
        // pack f32 tile -> bf16-pair uints, coalesced store
        #pragma unroll
        for (int i = 0; i < 4; i++) {
            int idx = tid + i * 256;
            int row = idx >> 6, cp = idx & 63;
            int rr = r0 + row;
            if (rr < nrows) {
                float2 f = *reinterpret_cast<const float2*>(&tile[row][cp * 2]);
                Yb[(size_t)rr * 64 + cp] = bfpack(f.x, f.y);
            }
        }
        if (ATT && tid < 64) {
            int rr2 = tid >> 2, h = tid & 3;
            if (r0 + rr2 < nrows) {
                float ps = 0.f, pd = 0.f;
                #pragma unroll
                for (int j = 0; j < 32; j++) {
                    float v = tile[rr2][h * 32 + j];
                    ps += v * as_sh[h * 32 + j];
                    pd += v * ad_sh[h * 32 + j];
                }
                a_src[(size_t)(r0 + rr2) * 4 + h] = ps;
                a_dst[(size_t)(r0 + rr2) * 4 + h] = pd;
            }
        }
    }
}

// ---------- K5: GAT aggregate — wave/node, alpha in LDS, bf16-pair gather
__global__ __launch_bounds__(256)
void k_gat_agg(const int* __restrict__ offsets, const int* __restrict__ csr_src,
               const float* __restrict__ a_src, const float* __restrict__ a_dst,
               const unsigned* __restrict__ xwb, const float* __restrict__ bias,
               const float* __restrict__ g1, const float* __restrict__ b1,
               const float* __restrict__ mu1, const float* __restrict__ var1,
               float* __restrict__ hout, int n) {
    __shared__ int   src_sh[4][64];
    __shared__ float al_sh[4][4][64];
    int lane = threadIdx.x & 63;
    int wv   = threadIdx.x >> 6;
    int wid  = (blockIdx.x * blockDim.x + threadIdx.x) >> 6;
    int nw   = (gridDim.x * blockDim.x) >> 6;
    int hP   = lane >> 4;
    int c0 = lane * 2, c1 = c0 + 1;
    float bi0 = bias[c0], bi1 = bias[c1];
    float A0 = g1[c0] * rsqrtf(var1[c0] + BN_EPS);
    float A1 = g1[c1] * rsqrtf(var1[c1] + BN_EPS);
    float B0 = b1[c0] - mu1[c0] * A0;
    float B1 = b1[c1] - mu1[c1] * A1;
    for (int node = wid; node < n; node += nw) {
        int beg = offsets[node], end = offsets[node + 1];
        int rowlen = end - beg, total = rowlen + 1;
        float4 adv = *reinterpret_cast<const float4*>(&a_dst[(size_t)node * 4]);
        int sv = (lane < rowlen) ? csr_src[beg + lane] : node;
        float4 as4 = *reinterpret_cast<const float4*>(&a_src[(size_t)sv * 4]);
        float e0 = leaky_f(as4.x + adv.x), e1 = leaky_f(as4.y + adv.y);
        float e2 = leaky_f(as4.z + adv.z), e3 = leaky_f(as4.w + adv.w);
        float m[4] = {-FLT_MAX, -FLT_MAX, -FLT_MAX, -FLT_MAX};
        if (lane < total) { m[0] = e0; m[1] = e1; m[2] = e2; m[3] = e3; }
        for (int i = lane + 64; i < total; i += 64) {
            int src = (i < rowlen) ? csr_src[beg + i] : node;
            float4 a4 = *reinterpret_cast<const float4*>(&a_src[(size_t)src * 4]);
            m[0] = fmaxf(m[0], leaky_f(a4.x + adv.x));
            m[1] = fmaxf(m[1], leaky_f(a4.y + adv.y));
            m[2] = fmaxf(m[2], leaky_f(a4.z + adv.z));
            m[3] = fmaxf(m[3], leaky_f(a4.w + adv.w));
        }
        #pragma unroll
        for (int off = 32; off; off >>= 1) {
            #pragma unroll
            for (int h = 0; h < 4; h++) m[h] = fmaxf(m[h], __shfl_xor(m[h], off));
        }
        float ex[4] = {0.f, 0.f, 0.f, 0.f};
        if (lane < total) {
            ex[0] = expf(e0 - m[0]); ex[1] = expf(e1 - m[1]);
            ex[2] = expf(e2 - m[2]); ex[3] = expf(e3 - m[3]);
        }
        float s[4] = {ex[0], ex[1], ex[2], ex[3]};
        for (int i = lane + 64; i < total; i += 64) {
            int src = (i < rowlen) ? csr_src[beg + i] : node;
            float4 a4 = *reinterpret_cast<const float4*>(&a_src[(size_t)src * 4]);
            s[0] += expf(leaky_f(a4.x + adv.x) - m[0]);
            s[1] += expf(leaky_f(a4.y + adv.y) - m[1]);
            s[2] += expf(leaky_f(a4.z + adv.z) - m[2]);
            s[3] += expf(leaky_f(a4.w + adv.w) - m[3]);
        }
        #pragma unroll
        for (int off = 32; off; off >>= 1) {
            #pragma unroll
            for (int h = 0; h < 4; h++) s[h] += __shfl_xor(s[h], off);
        }
        float inv[4];
        #pragma unroll
        for (int h = 0; h < 4; h++) inv[h] = 1.f / (s[h] + 1e-16f);
        src_sh[wv][lane] = sv;
        #pragma unroll
        for (int h = 0; h < 4; h++) al_sh[wv][h][lane] = ex[h] * inv[h];
        __builtin_amdgcn_wave_barrier();
        float acc0 = 0.f, acc1 = 0.f;
        int cnt = min(total, 64);
        for (int i = 0; i < cnt; i++) {
            int src  = src_sh[wv][i];
            float aP = al_sh[wv][hP][i];
            unsigned u = xwb[(size_t)src * 64 + lane];
            acc0 += aP * bflo(u);
            acc1 += aP * bfhi(u);
        }
        for (int base = 64; base < total; base += 64) {
            __builtin_amdgcn_wave_barrier();
            int i = base + lane;
            int src2 = node;
            float a0v = 0.f, a1v = 0.f, a2v = 0.f, a3v = 0.f;
            if (i < total) {
                if (i < rowlen) src2 = csr_src[beg + i];
                float4 a4 = *reinterpret_cast<const float4*>(&a_src[(size_t)src2 * 4]);
                a0v = expf(leaky_f(a4.x + adv.x) - m[0]) * inv[0];
                a1v = expf(leaky_f(a4.y + adv.y) - m[1]) * inv[1];
                a2v = expf(leaky_f(a4.z + adv.z) - m[2]) * inv[2];
                a3v = expf(leaky_f(a4.w + adv.w) - m[3]) * inv[3];
            }
            src_sh[wv][lane] = src2;
            al_sh[wv][0][lane] = a0v; al_sh[wv][1][lane] = a1v;
            al_sh[wv][2][lane] = a2v; al_sh[wv][3][lane] = a3v;
            __builtin_amdgcn_wave_barrier();
            int cnt2 = min(total - base, 64);
            for (int j = 0; j < cnt2; j++) {
                int src  = src_sh[wv][j];
                float aP = al_sh[wv][hP][j];
                unsigned u = xwb[(size_t)src * 64 + lane];
                acc0 += aP * bflo(u);
                acc1 += aP * bfhi(u);
            }
        }
        __builtin_amdgcn_wave_barrier();
        float vA = elu_f(acc0 + bi0);
        float vB = elu_f(acc1 + bi1);
        vA = vA * A0 + B0;
        vB = vB * A1 + B1;
        *reinterpret_cast<float2*>(&hout[(size_t)node * 128 + c0]) =
            make_float2(vA, vB);
    }
}

// ---------- K7: GCN aggregate — wave/node, bf16-pair gather + gate dot
__global__ __launch_bounds__(256)
void k_gcn_agg(const int* __restrict__ offsets, const int* __restrict__ csr_src,
               const float* __restrict__ dinv, const unsigned* __restrict__ hwb,
               const float* __restrict__ bias,
               const float* __restrict__ g2, const float* __restrict__ b2,
               const float* __restrict__ mu2, const float* __restrict__ var2,
               const float* __restrict__ gateW, const float* __restrict__ gateB,
               float* __restrict__ h2, float* __restrict__ gate, int n) {
    __shared__ int   src_sh[4][64];
    __shared__ float w_sh[4][64];
    int lane = threadIdx.x & 63;
    int wv   = threadIdx.x >> 6;
    int wid  = (blockIdx.x * blockDim.x + threadIdx.x) >> 6;
    int nw   = (gridDim.x * blockDim.x) >> 6;
    int c0 = lane * 2, c1 = c0 + 1;
    float bi0 = bias[c0], bi1 = bias[c1];
    float A0 = g2[c0] * rsqrtf(var2[c0] + BN_EPS);
    float A1 = g2[c1] * rsqrtf(var2[c1] + BN_EPS);
    float B0 = b2[c0] - mu2[c0] * A0;
    float B1 = b2[c1] - mu2[c1] * A1;
    float gw0 = gateW[c0], gw1 = gateW[c1], gB = gateB[0];
    for (int node = wid; node < n; node += nw) {
        int beg = offsets[node], end = offsets[node + 1];
        int rowlen = end - beg;
        float dn = dinv[node];
        unsigned us = hwb[(size_t)node * 64 + lane];
        float acc0 = dn * dn * bflo(us);
        float acc1 = dn * dn * bfhi(us);
        for (int base = 0; base < rowlen; base += 64) {
            __builtin_amdgcn_wave_barrier();
            int i = base + lane;
            int src2 = node;
            float wv2 = 0.f;
            if (i < rowlen) { src2 = csr_src[beg + i]; wv2 = dinv[src2] * dn; }
            src_sh[wv][lane] = src2;
            w_sh[wv][lane]   = wv2;
            __builtin_amdgcn_wave_barrier();
            int cnt = min(rowlen - base, 64);
            for (int j = 0; j < cnt; j++) {
                int src = src_sh[wv][j];
                float w = w_sh[wv][j];
                unsigned u = hwb[(size_t)src * 64 + lane];
                acc0 += w * bflo(u);
                acc1 += w * bfhi(u);
            }
        }
        __builtin_amdgcn_wave_barrier();
        float vA = elu_f(acc0 + bi0);
        float vB = elu_f(acc1 + bi1);
        vA = vA * A0 + B0;
        vB = vB * A1 + B1;
        *reinterpret_cast<float2*>(&h2[(size_t)node * 128 + c0]) =
            make_float2(vA, vB);
        float p = vA * gw0 + vB * gw1;
        #pragma unroll
        for (int off = 32; off; off >>= 1) p += __shfl_xor(p, off);
        if (lane == 0) gate[node] = p + gB;
    }
}

// -------------------------- K8: GlobalAttention pool, one block per graph
__device__ __forceinline__ int lbound(const int* a, int n, int key) {
    int lo = 0, hi = n;
    while (lo < hi) { int mid = (lo + hi) >> 1; if (a[mid] < key) lo = mid + 1; else hi = mid; }
    return lo;
}

__global__ __launch_bounds__(256)
void k_pool(const int* __restrict__ batch, const float* __restrict__ gate,
            const float* __restrict__ h2, float* __restrict__ grep, int n) {
    int b = blockIdx.x, tid = threadIdx.x;
    __shared__ float red[256];
    __shared__ float sc_sh[256];
    int start = lbound(batch, n, b);
    int end   = lbound(batch, n, b + 1);
    float m = -FLT_MAX;
    for (int i = start + tid; i < end; i += 256) m = fmaxf(m, gate[i]);
    red[tid] = m; __syncthreads();
    for (int s2 = 128; s2 > 0; s2 >>= 1) {
        if (tid < s2) red[tid] = fmaxf(red[tid], red[tid + s2]);
        __syncthreads();
    }
    m = red[0]; __syncthreads();
    float s = 0.f;
    for (int i = start + tid; i < end; i += 256) s += expf(gate[i] - m);
    red[tid] = s; __syncthreads();
    for (int s2 = 128; s2 > 0; s2 >>= 1) {
        if (tid < s2) red[tid] += red[tid + s2];
        __syncthreads();
    }
    float inv = 1.f / (red[0] + 1e-16f);
    __syncthreads();
    int j = tid & 127, half = tid >> 7;
    float acc = 0.f;
    for (int base = start; base < end; base += 256) {
        int cnt = min(256, end - base);
        __syncthreads();
        if (tid < cnt) sc_sh[tid] = expf(gate[base + tid] - m) * inv;
        __syncthreads();
        for (int ii = half; ii < cnt; ii += 2)
            acc += sc_sh[ii] * h2[(size_t)(base + ii) * 128 + j];
    }
    red[tid] = acc; __syncthreads();
    if (half == 0) grep[b * 128 + j] = red[j] + red[128 + j];
}

// ---- K9: LSTM — 512 thr (1 gate row/thread), weights in VGPR via STATIC
//      macro-unrolled indices (guaranteed no scratch), readlane h-broadcast.
#define R4(M, K)  M(K) M((K)+1) M((K)+2) M((K)+3)
#define R8(M, K)  R4(M, K) R4(M, (K)+4)
#define R16(M, K) R8(M, K) R8(M, (K)+8)
#define R32(M, K) R16(M, K) R16(M, (K)+16)
#define R64(M, K) R32(M, K) R32(M, (K)+32)

__global__ __launch_bounds__(512, 2)
void k_lstm(const float* __restrict__ quant, const float* __restrict__ Wih,
            const float* __restrict__ Whh, const float* __restrict__ bih,
            const float* __restrict__ bhh, const float* __restrict__ grep,
            const float* __restrict__ fcW, const float* __restrict__ fcB,
            float* __restrict__ out) {
    int b = blockIdx.x, t = threadIdx.x, lane = t & 63;
    __shared__ __align__(16) float x_sh[KT * KQD];   // 6.4 KB
    __shared__ float h_sh[KLH];
    __shared__ float gp_sh[4 * KLH];
    __shared__ float red[KLH];
    // stage quant row (block-uniform) into LDS
    const float4* qrow = reinterpret_cast<const float4*>(&quant[(size_t)b * (KT * KQD)]);
    for (int idx = t; idx < (KT * KQD) / 4; idx += 512)
        reinterpret_cast<float4*>(x_sh)[idx] = qrow[idx];
    // weights -> registers with literal indices (SROA-safe)
    float whhf[128], wihf[32];
    int g = t;
#define WHL(K) { float4 q_ = *reinterpret_cast<const float4*>(&Whh[(size_t)g * 128 + 4 * (K)]); \
    whhf[4*(K)] = q_.x; whhf[4*(K)+1] = q_.y; whhf[4*(K)+2] = q_.z; whhf[4*(K)+3] = q_.w; }
    R32(WHL, 0)
#define WIL(K) { float4 q_ = *reinterpret_cast<const float4*>(&Wih[(size_t)g * 32 + 4 * (K)]); \
    wihf[4*(K)] = q_.x; wihf[4*(K)+1] = q_.y; wihf[4*(K)+2] = q_.z; wihf[4*(K)+3] = q_.w; }
    R8(WIL, 0)
    float bias = bih[g] + bhh[g];
    float c = 0.f;
    if (t < KLH) h_sh[t] = 0.f;
    __syncthreads();
    for (int s = 0; s < KT; s++) {
        float h0 = h_sh[lane];          // h[0..63] spread over lanes
        float h1 = h_sh[64 + lane];     // h[64..127]
        const float4* x4 = reinterpret_cast<const float4*>(&x_sh[s * KQD]);
        float4 xq0 = x4[0], xq1 = x4[1], xq2 = x4[2], xq3 = x4[3];
        float4 xq4 = x4[4], xq5 = x4[5], xq6 = x4[6], xq7 = x4[7];
        float a = bias;
#define XM4(Q, K) a = fmaf(Q.x, wihf[K], a); a = fmaf(Q.y, wihf[(K)+1], a); \
                  a = fmaf(Q.z, wihf[(K)+2], a); a = fmaf(Q.w, wihf[(K)+3], a);
        XM4(xq0, 0)  XM4(xq1, 4)  XM4(xq2, 8)  XM4(xq3, 12)
        XM4(xq4, 16) XM4(xq5, 20) XM4(xq6, 24) XM4(xq7, 28)
#define HM(K) a = fmaf(rdlane(((K) < 64 ? h0 : h1), (K) & 63), whhf[K], a);
        R64(HM, 0) R64(HM, 64)
        gp_sh[t] = a;
        __syncthreads();
        if (t < KLH) {
            float ig = sigm_f(gp_sh[t]);
            float fg = sigm_f(gp_sh[KLH + t]);
            float gg = tanhf (gp_sh[2 * KLH + t]);
            float og = sigm_f(gp_sh[3 * KLH + t]);
            c = fg * c + ig * gg;
            h_sh[t] = og * tanhf(c);
        }
        __syncthreads();
    }
    if (t < KLH)
        red[t] = fcW[t] * grep[b * 128 + t] + fcW[128 + t] * h_sh[t];
    __syncthreads();
    for (int s2 = 64; s2 > 0; s2 >>= 1) {
        if (t < s2) red[t] += red[t + s2];
        __syncthreads();
    }
    if (t == 0) out[b] = red[0] + fcB[0];
}

// ----------------------------------------------------------------- launcher
extern "C" void kernel_launch(void* const* d_in, const int* in_sizes, int n_in,
                              void* d_out, int out_size, void* d_ws, size_t ws_size,
                              hipStream_t stream) {
    const float* x     = (const float*)d_in[0];
    const int*   ei    = (const int*)  d_in[1];
    const int*   batch = (const int*)  d_in[2];
    const float* quant = (const float*)d_in[3];
    const float* gatW  = (const float*)d_in[4];
    const float* attS  = (const float*)d_in[5];
    const float* attD  = (const float*)d_in[6];
    const float* gatB  = (const float*)d_in[7];
    const float* bn1g  = (const float*)d_in[8];
    const float* bn1b  = (const float*)d_in[9];
    const float* bn1m  = (const float*)d_in[10];
    const float* bn1v  = (const float*)d_in[11];
    const float* gcnW  = (const float*)d_in[12];
    const float* gcnB  = (const float*)d_in[13];
    const float* bn2g  = (const float*)d_in[14];
    const float* bn2b  = (const float*)d_in[15];
    const float* bn2m  = (const float*)d_in[16];
    const float* bn2v  = (const float*)d_in[17];
    const float* gateW = (const float*)d_in[18];
    const float* gateB = (const float*)d_in[19];
    const float* Wih   = (const float*)d_in[20];
    const float* Whh   = (const float*)d_in[21];
    const float* bih   = (const float*)d_in[22];
    const float* bhh   = (const float*)d_in[23];
    const float* fcW   = (const float*)d_in[24];
    const float* fcB   = (const float*)d_in[25];

    int N = in_sizes[0] / KIN;
    int E = in_sizes[1] / 2;
    int B = in_sizes[3] / (KT * KQD);

    char* ws = (char*)d_ws;
    size_t off = 0;
    auto alloc = [&](size_t bytes) -> void* {
        void* p = ws + off;
        off += (bytes + 511) & ~(size_t)511;
        return p;
    };
    int*      deg     = (int*)     alloc((size_t)N * 4);
    int*      offsets = (int*)     alloc((size_t)(N + 1) * 4);
    int*      cursor  = (int*)     alloc((size_t)N * 4);
    float*    dinv    = (float*)   alloc((size_t)N * 4);
    int*      csr_src = (int*)     alloc((size_t)E * 4);
    float*    a_src   = (float*)   alloc((size_t)N * 16);
    float*    a_dst   = (float*)   alloc((size_t)N * 16);
    unsigned* xwb     = (unsigned*)alloc((size_t)N * 256);  // bf16 gemm out; reused as hwb
    float*    hbuf    = (float*)   alloc((size_t)N * 512);  // f32 gat out; reused as h2
    float*    gate    = (float*)   alloc((size_t)N * 4);
    float*    grep    = (float*)   alloc((size_t)B * 512);

    hipMemsetAsync(deg, 0, (size_t)N * 4, stream);
    int eb = (E + 255) / 256;
    k_deg <<<eb, 256, 0, stream>>>(ei, E, deg);
    k_scan<<<1, 1024, 0, stream>>>(deg, N, offsets, cursor, dinv);
    k_fill<<<eb, 256, 0, stream>>>(ei, E, cursor, csr_src);

    k_gemm_mfma<true ><<<512, 256, 0, stream>>>(x, gatW, xwb, N, attS, attD, a_src, a_dst);
    k_gat_agg<<<2048, 256, 0, stream>>>(offsets, csr_src, a_src, a_dst, xwb, gatB,
                                        bn1g, bn1b, bn1m, bn1v, hbuf, N);
    k_gemm_mfma<false><<<512, 256, 0, stream>>>(hbuf, gcnW, xwb, N,
                                                nullptr, nullptr, nullptr, nullptr);
    k_gcn_agg<<<2048, 256, 0, stream>>>(offsets, csr_src, dinv, xwb, gcnB,
                                        bn2g, bn2b, bn2m, bn2v, gateW, gateB,
                                        hbuf, gate, N);
    k_pool<<<B, 256, 0, stream>>>(batch, gate, hbuf, grep, N);
    k_lstm<<<B, 512, 0, stream>>>(quant, Wih, Whh, bih, bhh, grep, fcW, fcB,
                                  (float*)d_out);
}